// Round 16
// baseline (27144.904 us; speedup 1.0000x reference)
//
#include <hip/hip_runtime.h>
#include <math.h>

#define Bq 256
#define Tq 200
#define INq 33
#define Hq 2048
#define OUTq 4

typedef __attribute__((ext_vector_type(8))) short bf16x8;
typedef __attribute__((ext_vector_type(16))) float f32x16;
typedef __attribute__((ext_vector_type(4))) unsigned short us4;

#define MFMA32(A, B, C) __builtin_amdgcn_mfma_f32_32x32x16_bf16((A), (B), (C), 0, 0, 0)

__device__ __forceinline__ unsigned short f32_to_bf16(float f) {
  unsigned u = __float_as_uint(f);
  unsigned r = 0x7FFFu + ((u >> 16) & 1u);
  return (unsigned short)((u + r) >> 16);
}
__device__ __forceinline__ float bf16_to_f32(unsigned short h) {
  return __uint_as_float((unsigned)h << 16);
}

// ws byte offsets
#define WS_W1     0ull
#define WS_W2     8388608ull
#define WS_W3     16777216ull
#define WS_SLABF0 25165824ull
#define WS_SLABF1 27262976ull
#define WS_APARTS 29360128ull           // ap[pp][part] = + (pp*3+part)*1048576
#define WS_WIT    35651584ull           // WiT [33][2048] f32
#define WS_BAR    35921920ull           // barrier counter (64 B)
#define WS_TOTAL  35921984ull

#define DOT4(ACC, Av, Bv) \
  ACC = fmaf((Av).x, (Bv).x, ACC); ACC = fmaf((Av).y, (Bv).y, ACC); \
  ACC = fmaf((Av).z, (Bv).z, ACC); ACC = fmaf((Av).w, (Bv).w, ACC)

// ---------------------------------------------------------------------------
// Pack Wrec -> 3 bf16 parts in MFMA-fragment order (verified R11-R15)
// ---------------------------------------------------------------------------
__global__ __launch_bounds__(256) void conv_wrec(
    const float* __restrict__ W, unsigned short* __restrict__ w1,
    unsigned short* __restrict__ w2, unsigned short* __restrict__ w3)
{
  const int g   = blockIdx.x * 256 + threadIdx.x;
  const int col = g >> 7;
  const int kc  = g & 127;
  const float* src = W + (size_t)col * Hq + kc * 16;
  unsigned short s1[16], s2[16], s3[16];
#pragma unroll
  for (int j = 0; j < 16; ++j) {
    float v = src[j];
    unsigned short b1 = f32_to_bf16(v);
    float r1 = v - bf16_to_f32(b1);
    unsigned short b2 = f32_to_bf16(r1);
    float r2 = r1 - bf16_to_f32(b2);
    s1[j] = b1; s2[j] = b2; s3[j] = f32_to_bf16(r2);
  }
  const size_t o_lo = ((size_t)(kc * 64 + (col >> 5)) * 64 + (col & 31)) * 8;
  const size_t o_hi = o_lo + 256;
#pragma unroll
  for (int jj = 0; jj < 2; ++jj) {
    *(us4*)&w1[o_lo + jj * 4] = *(us4*)&s1[jj * 4];
    *(us4*)&w1[o_hi + jj * 4] = *(us4*)&s1[8 + jj * 4];
    *(us4*)&w2[o_lo + jj * 4] = *(us4*)&s2[jj * 4];
    *(us4*)&w2[o_hi + jj * 4] = *(us4*)&s2[8 + jj * 4];
    *(us4*)&w3[o_lo + jj * 4] = *(us4*)&s3[jj * 4];
    *(us4*)&w3[o_hi + jj * 4] = *(us4*)&s3[8 + jj * 4];
  }
}

// Wi2h [2048][33] -> WiT [33][2048]; thread 0 of block 0 zeroes the barrier
__global__ __launch_bounds__(256) void conv_wi(
    const float* __restrict__ Wi2h, float* __restrict__ WiT,
    unsigned* __restrict__ bar)
{
  const int g = blockIdx.x * 256 + threadIdx.x;
  if (g == 0) *bar = 0u;
  if (g >= INq * Hq) return;
  const int i = g >> 11;
  const int c = g & 2047;
  WiT[(size_t)i * Hq + c] = Wi2h[(size_t)c * INq + i];
}

// ---------------------------------------------------------------------------
// Persistent MFMA kernel: all 200 steps + final head in ONE dispatch.
// 256 WGs x 512 thr (cooperative, 1 WG/CU). Per-step body identical to R11
// (packed fragments, 8-product split, fixed-order combine). Steps separated
// by a monotonic atomic barrier (release fence -> add -> relaxed spin ->
// acquire fence), NOT grid.sync().
// ---------------------------------------------------------------------------
__global__ __launch_bounds__(512, 1) void rnn_persist(
    const float* __restrict__ x, const float* __restrict__ noise,
    const float* __restrict__ WiT, const float* __restrict__ Wh2o,
    const unsigned short* __restrict__ w1, const unsigned short* __restrict__ w2,
    const unsigned short* __restrict__ w3,
    float* __restrict__ slab0, float* __restrict__ slab1,
    unsigned short* __restrict__ ap0_1, unsigned short* __restrict__ ap0_2,
    unsigned short* __restrict__ ap0_3,
    unsigned short* __restrict__ ap1_1, unsigned short* __restrict__ ap1_2,
    unsigned short* __restrict__ ap1_3,
    float* __restrict__ out_h, float* __restrict__ out_o,
    unsigned* __restrict__ bar)
{
  __shared__ float P[4 * 2176 + 32];     // [4 q][32 row][68] + proj scratch

  const int wg  = blockIdx.x;
  const int tid = threadIdx.x;

  const int L  = (wg & 7) * 32 + (wg >> 3);   // XCD c owns col-tiles [4c,4c+4)
  const int TC = L >> 3;
  const int TR = L & 7;

  const int lane = tid & 63;
  const int wv   = __builtin_amdgcn_readfirstlane(tid >> 6);
  const int ct   = wv & 1;
  const int q    = wv >> 1;

  for (int t = 0; t <= Tq; ++t) {
    // slab parity: pc = t&1 receives h_t; pp holds h_{t-1}
    const int pc = t & 1;
    const float* hprevF = pc ? slab0 : slab1;
    float*       houtF  = pc ? slab1 : slab0;
    const unsigned short* a1 = pc ? ap0_1 : ap1_1;
    const unsigned short* a2 = pc ? ap0_2 : ap1_2;
    const unsigned short* a3 = pc ? ap0_3 : ap1_3;
    unsigned short* o1 = pc ? ap1_1 : ap0_1;
    unsigned short* o2 = pc ? ap1_2 : ap0_2;
    unsigned short* o3 = pc ? ap1_3 : ap0_3;

    // ---- softmax head for step t-1, batch row wg ----
    if (t > 0) {
      float* ps = P + 4 * 2176;
      const int i4 = tid * 4;
      float4 hv  = *(const float4*)(hprevF + (size_t)wg * Hq + i4);
      float4 q0v = *(const float4*)(Wh2o + 0 * Hq + i4);
      float4 q1v = *(const float4*)(Wh2o + 1 * Hq + i4);
      float4 q2v = *(const float4*)(Wh2o + 2 * Hq + i4);
      float4 q3v = *(const float4*)(Wh2o + 3 * Hq + i4);
      float s0 = 0.f, s1 = 0.f, s2 = 0.f, s3 = 0.f;
      DOT4(s0, hv, q0v); DOT4(s1, hv, q1v); DOT4(s2, hv, q2v); DOT4(s3, hv, q3v);
#pragma unroll
      for (int m = 1; m <= 32; m <<= 1) {
        s0 += __shfl_xor(s0, m); s1 += __shfl_xor(s1, m);
        s2 += __shfl_xor(s2, m); s3 += __shfl_xor(s3, m);
      }
      if ((tid & 63) == 0) {
        ps[wv * 4 + 0] = s0; ps[wv * 4 + 1] = s1;
        ps[wv * 4 + 2] = s2; ps[wv * 4 + 3] = s3;
      }
      __syncthreads();
      if (tid == 0) {
        float t0 = 0.f, t1 = 0.f, t2 = 0.f, t3 = 0.f;
#pragma unroll
        for (int w = 0; w < 8; ++w) {   // fixed order
          t0 += ps[w * 4 + 0]; t1 += ps[w * 4 + 1];
          t2 += ps[w * 4 + 2]; t3 += ps[w * 4 + 3];
        }
        float m  = fmaxf(fmaxf(t0, t1), fmaxf(t2, t3));
        float e0 = expf(t0 - m), e1 = expf(t1 - m);
        float e2 = expf(t2 - m), e3 = expf(t3 - m);
        float inv = 1.0f / (e0 + e1 + e2 + e3);
        float* op = out_o + ((size_t)wg * Tq + (t - 1)) * OUTq;
        op[0] = e0 * inv; op[1] = e1 * inv; op[2] = e2 * inv; op[3] = e3 * inv;
      }
      __syncthreads();
    }

    if (t == Tq) break;                 // last iteration: head only

    f32x16 accA, accB;
#pragma unroll
    for (int i = 0; i < 16; ++i) { accA[i] = 0.f; accB[i] = 0.f; }

    if (t > 0) {
      const int kc0 = q * 32;
      const unsigned short* pa1 = a1 + ((size_t)(kc0 * 8 + TR) * 64 + lane) * 8;
      const unsigned short* pa2 = a2 + ((size_t)(kc0 * 8 + TR) * 64 + lane) * 8;
      const unsigned short* pa3 = a3 + ((size_t)(kc0 * 8 + TR) * 64 + lane) * 8;
      const int cb = TC * 2 + ct;
      const unsigned short* pb1 = w1 + ((size_t)(kc0 * 64 + cb) * 64 + lane) * 8;
      const unsigned short* pb2 = w2 + ((size_t)(kc0 * 64 + cb) * 64 + lane) * 8;
      const unsigned short* pb3 = w3 + ((size_t)(kc0 * 64 + cb) * 64 + lane) * 8;

#define LA(P_, c) (*(const bf16x8*)((P_) + ((size_t)(c) << 12)))
#define LB(P_, c) (*(const bf16x8*)((P_) + ((size_t)(c) << 15)))
      bf16x8 A1x = LA(pa1, 0), A2x = LA(pa2, 0), A3x = LA(pa3, 0);
      bf16x8 B1x = LB(pb1, 0), B2x = LB(pb2, 0), B3x = LB(pb3, 0);
      bf16x8 A1y = LA(pa1, 1), A2y = LA(pa2, 1), A3y = LA(pa3, 1);
      bf16x8 B1y = LB(pb1, 1), B2y = LB(pb2, 1), B3y = LB(pb3, 1);

      for (int s = 0; s < 32; s += 2) {
        accA = MFMA32(A1x, B1x, accA);  accB = MFMA32(A2x, B1x, accB);
        accB = MFMA32(A1x, B2x, accB);  accA = MFMA32(A2x, B2x, accA);
        accA = MFMA32(A3x, B1x, accA);  accB = MFMA32(A1x, B3x, accB);
        accB = MFMA32(A3x, B2x, accB);  accA = MFMA32(A2x, B3x, accA);
        if (s + 2 < 32) {
          A1x = LA(pa1, s + 2); A2x = LA(pa2, s + 2); A3x = LA(pa3, s + 2);
          B1x = LB(pb1, s + 2); B2x = LB(pb2, s + 2); B3x = LB(pb3, s + 2);
        }
        accA = MFMA32(A1y, B1y, accA);  accB = MFMA32(A2y, B1y, accB);
        accB = MFMA32(A1y, B2y, accB);  accA = MFMA32(A2y, B2y, accA);
        accA = MFMA32(A3y, B1y, accA);  accB = MFMA32(A1y, B3y, accB);
        accB = MFMA32(A3y, B2y, accB);  accA = MFMA32(A2y, B3y, accA);
        if (s + 3 < 32) {
          A1y = LA(pa1, s + 3); A2y = LA(pa2, s + 3); A3y = LA(pa3, s + 3);
          B1y = LB(pb1, s + 3); B2y = LB(pb2, s + 3); B3y = LB(pb3, s + 3);
        }
      }
#undef LA
#undef LB

      const int prow0 = (lane >> 5) * 4;
      float* pw = P + q * 2176 + (ct * 32 + (lane & 31));
#pragma unroll
      for (int rr = 0; rr < 16; ++rr) {
        const int row = prow0 + (rr & 3) + 8 * (rr >> 2);
        pw[row * 68] = accA[rr] + accB[rr];
      }
    }
    __syncthreads();

    // ---- 512-thread epilogue ----
    {
      const int row = tid >> 4;
      const int j0l = (tid & 15) * 4;
      const int b   = TR * 32 + row;
      const int gc  = TC * 64 + j0l;

      float e0 = 0.f, e1 = 0.f, e2 = 0.f, e3 = 0.f;
      if (t > 0) {
#pragma unroll
        for (int qq = 0; qq < 4; ++qq) { // fixed order
          const float* pr = P + qq * 2176 + row * 68 + j0l;
          e0 += pr[0]; e1 += pr[1]; e2 += pr[2]; e3 += pr[3];
        }
      }

      const float* xb = x + ((size_t)b * Tq + t) * INq;
#pragma unroll
      for (int i = 0; i < INq; ++i) {
        float xv = xb[i];
        float4 wv4 = *(const float4*)(WiT + (size_t)i * Hq + gc);
        e0 = fmaf(xv, wv4.x, e0); e1 = fmaf(xv, wv4.y, e1);
        e2 = fmaf(xv, wv4.z, e2); e3 = fmaf(xv, wv4.w, e3);
      }

      float4 nz = *(const float4*)(noise + ((size_t)t * Bq + b) * Hq + gc);
      e0 += nz.x; e1 += nz.y; e2 += nz.z; e3 += nz.w;

      float4 hp = make_float4(0.f, 0.f, 0.f, 0.f);
      if (t > 0) hp = *(const float4*)(hprevF + (size_t)b * Hq + gc);

      float4 o;
      o.x = fmaf(fmaxf(e0, 0.f), 0.1f, 0.9f * hp.x);
      o.y = fmaf(fmaxf(e1, 0.f), 0.1f, 0.9f * hp.y);
      o.z = fmaf(fmaxf(e2, 0.f), 0.1f, 0.9f * hp.z);
      o.w = fmaf(fmaxf(e3, 0.f), 0.1f, 0.9f * hp.w);

      *(float4*)(out_h + ((size_t)b * Tq + t) * Hq + gc) = o;
      *(float4*)(houtF + (size_t)b * Hq + gc) = o;

      us4 p1v, p2v, p3v;
      float ov[4] = { o.x, o.y, o.z, o.w };
#pragma unroll
      for (int c = 0; c < 4; ++c) {
        unsigned short b1 = f32_to_bf16(ov[c]);
        float r1 = ov[c] - bf16_to_f32(b1);
        unsigned short b2 = f32_to_bf16(r1);
        float r2 = r1 - bf16_to_f32(b2);
        p1v[c] = b1; p2v[c] = b2; p3v[c] = f32_to_bf16(r2);
      }
      const size_t apo = ((size_t)((gc >> 4) * 8 + TR) * 64
                          + ((gc >> 3) & 1) * 32 + row) * 8 + (gc & 7);
      *(us4*)&o1[apo] = p1v;
      *(us4*)&o2[apo] = p2v;
      *(us4*)&o3[apo] = p3v;
    }

    // ---- inter-step barrier: monotonic counter, release/acquire fences ----
    __threadfence();                    // release this thread's writes
    __syncthreads();                    // whole WG has released
    if (tid == 0) {
      __hip_atomic_fetch_add(bar, 1u, __ATOMIC_RELEASE, __HIP_MEMORY_SCOPE_AGENT);
      const unsigned target = 256u * (unsigned)(t + 1);
      while (__hip_atomic_load(bar, __ATOMIC_RELAXED, __HIP_MEMORY_SCOPE_AGENT) < target)
        __builtin_amdgcn_s_sleep(1);
    }
    __syncthreads();
    __threadfence();                    // acquire for all threads
  }
}

// ===========================================================================
// Fallback (R9 f32 path) if workspace too small.
// ===========================================================================
#define BKq 32
#define NST 16
__device__ __forceinline__ int swz(int row, int k) {
  return k ^ (((row >> 2) & 7) << 2);
}

__global__ __launch_bounds__(256) void proj_tail(
    const float* __restrict__ hbase, size_t rstride,
    const float* __restrict__ Wh2o, float* __restrict__ out_o, int tp)
{
  const int tid = threadIdx.x;
  const int r  = blockIdx.x * 64 + (tid >> 2);
  const int p4 = tid & 3;
  const float* hp = hbase + (size_t)r * rstride;
  float a0 = 0.f, a1 = 0.f, a2 = 0.f, a3 = 0.f;
  const int k0 = p4 * 512;
#pragma unroll 4
  for (int k = k0; k < k0 + 512; k += 4) {
    float4 hv = *(const float4*)(hp + k);
    float4 w0 = *(const float4*)(Wh2o + 0 * Hq + k);
    float4 w1 = *(const float4*)(Wh2o + 1 * Hq + k);
    float4 w2 = *(const float4*)(Wh2o + 2 * Hq + k);
    float4 w3 = *(const float4*)(Wh2o + 3 * Hq + k);
    DOT4(a0, hv, w0); DOT4(a1, hv, w1); DOT4(a2, hv, w2); DOT4(a3, hv, w3);
  }
  a0 += __shfl_xor(a0, 1); a1 += __shfl_xor(a1, 1);
  a2 += __shfl_xor(a2, 1); a3 += __shfl_xor(a3, 1);
  a0 += __shfl_xor(a0, 2); a1 += __shfl_xor(a1, 2);
  a2 += __shfl_xor(a2, 2); a3 += __shfl_xor(a3, 2);
  if (p4 == 0) {
    float m  = fmaxf(fmaxf(a0, a1), fmaxf(a2, a3));
    float e0 = expf(a0 - m), e1 = expf(a1 - m);
    float e2 = expf(a2 - m), e3 = expf(a3 - m);
    float inv = 1.0f / (e0 + e1 + e2 + e3);
    float* op = out_o + ((size_t)r * Tq + tp) * OUTq;
    op[0] = e0 * inv; op[1] = e1 * inv; op[2] = e2 * inv; op[3] = e3 * inv;
  }
}

template<bool SLAB>
__global__ __launch_bounds__(512, 2) void rnn_step(
    const float* __restrict__ x, const float* __restrict__ noise,
    const float* __restrict__ Wi2h, const float* __restrict__ Wrec,
    const float* __restrict__ Wh2o, float* __restrict__ out_h,
    float* __restrict__ out_o, const float* __restrict__ slabP,
    float* __restrict__ slabT, int t)
{
  constexpr size_t HSTR = SLAB ? (size_t)Hq : (size_t)Tq * Hq;
  __shared__ float smem[24576];
  const int wg  = blockIdx.x;
  const int tid = threadIdx.x;
  const int L  = (wg & 7) * 32 + (wg >> 3);
  const int TC = L >> 3;
  const int TR = L & 7;
  const int q  = tid >> 7;
  const int qt = tid & 127;
  const int tx = qt & 15;
  const int ty = qt >> 4;
  const int m0 = ty * 4, n0 = tx * 4;
  const int b0 = TR * 32 + m0;
  const int j0 = TC * 64 + n0;
  const int kb = q * 512;
  const float* hPrev = SLAB ? slabP : (out_h + (size_t)(t > 0 ? t - 1 : 0) * Hq);
  const int sm  = ((qt & 7) << 2) | ((qt >> 3) & 3);
  const int skh = ((qt >> 5) & 3) * 8;
  const int sn  = (((qt >> 5) & 1) << 5) | ((qt & 7) << 2) | ((qt >> 3) & 3);
  const int snk = ((qt >> 6) & 1) * 16;
  const float* gA = hPrev + (size_t)(TR * 32 + sm) * HSTR + kb + skh;
  const float* gB = Wrec + (size_t)(TC * 64 + sn) * Hq + kb + snk;
  float4 sA0, sA1, sB0, sB1, sB2, sB3;
  if (t > 0) {
    sA0 = *(const float4*)(gA);      sA1 = *(const float4*)(gA + 4);
    sB0 = *(const float4*)(gB);      sB1 = *(const float4*)(gB + 4);
    sB2 = *(const float4*)(gB + 8);  sB3 = *(const float4*)(gB + 12);
  }
  if (t > 0) {
    const int i4 = tid * 4;
    float4 hv = *(const float4*)(hPrev + (size_t)wg * HSTR + i4);
    float4 w0 = *(const float4*)(Wh2o + 0 * Hq + i4);
    float4 w1 = *(const float4*)(Wh2o + 1 * Hq + i4);
    float4 w2 = *(const float4*)(Wh2o + 2 * Hq + i4);
    float4 w3 = *(const float4*)(Wh2o + 3 * Hq + i4);
    float a0 = 0.f, a1 = 0.f, a2 = 0.f, a3 = 0.f;
    DOT4(a0, hv, w0); DOT4(a1, hv, w1); DOT4(a2, hv, w2); DOT4(a3, hv, w3);
#pragma unroll
    for (int m = 1; m <= 32; m <<= 1) {
      a0 += __shfl_xor(a0, m); a1 += __shfl_xor(a1, m);
      a2 += __shfl_xor(a2, m); a3 += __shfl_xor(a3, m);
    }
    if ((tid & 63) == 0) {
      const int w = tid >> 6;
      smem[w * 4 + 0] = a0; smem[w * 4 + 1] = a1;
      smem[w * 4 + 2] = a2; smem[w * 4 + 3] = a3;
    }
    __syncthreads();
    if (tid == 0) {
      float s0 = 0.f, s1 = 0.f, s2 = 0.f, s3 = 0.f;
#pragma unroll
      for (int w = 0; w < 8; ++w) {
        s0 += smem[w * 4 + 0]; s1 += smem[w * 4 + 1];
        s2 += smem[w * 4 + 2]; s3 += smem[w * 4 + 3];
      }
      float m  = fmaxf(fmaxf(s0, s1), fmaxf(s2, s3));
      float e0 = expf(s0 - m), e1 = expf(s1 - m);
      float e2 = expf(s2 - m), e3 = expf(s3 - m);
      float inv = 1.0f / (e0 + e1 + e2 + e3);
      float* op = out_o + ((size_t)wg * Tq + (t - 1)) * OUTq;
      op[0] = e0 * inv; op[1] = e1 * inv; op[2] = e2 * inv; op[3] = e3 * inv;
    }
    __syncthreads();
  }
  float acc00 = 0.f, acc01 = 0.f, acc02 = 0.f, acc03 = 0.f;
  float acc10 = 0.f, acc11 = 0.f, acc12 = 0.f, acc13 = 0.f;
  float acc20 = 0.f, acc21 = 0.f, acc22 = 0.f, acc23 = 0.f;
  float acc30 = 0.f, acc31 = 0.f, acc32 = 0.f, acc33 = 0.f;
  if (t > 0) {
    {
      float* aL = smem + q * 2048;
      float* bL = smem + 8192 + q * 4096;
      *(float4*)(aL + sm * 32 + swz(sm, skh))      = sA0;
      *(float4*)(aL + sm * 32 + swz(sm, skh + 4))  = sA1;
      *(float4*)(bL + sn * 32 + swz(sn, snk))      = sB0;
      *(float4*)(bL + sn * 32 + swz(sn, snk + 4))  = sB1;
      *(float4*)(bL + sn * 32 + swz(sn, snk + 8))  = sB2;
      *(float4*)(bL + sn * 32 + swz(sn, snk + 12)) = sB3;
    }
    __syncthreads();
    const int aKey = ty << 2;
    const int bKey = (tx & 7) << 2;
    for (int s = 0; s < NST; ++s) {
      const int buf = s & 1;
      if (s + 1 < NST) {
        const int o = (s + 1) * BKq;
        sA0 = *(const float4*)(gA + o);      sA1 = *(const float4*)(gA + o + 4);
        sB0 = *(const float4*)(gB + o);      sB1 = *(const float4*)(gB + o + 4);
        sB2 = *(const float4*)(gB + o + 8);  sB3 = *(const float4*)(gB + o + 12);
      }
      const float* aT = smem + q * 2048 + buf * 1024 + ty * 128;
      const float* bT = smem + 8192 + q * 4096 + buf * 2048 + tx * 128;
#pragma unroll
      for (int k4 = 0; k4 < BKq; k4 += 4) {
        const float* ap = aT + (k4 ^ aKey);
        const float* bp = bT + (k4 ^ bKey);
        float4 A0 = *(const float4*)(ap);
        float4 A1 = *(const float4*)(ap + 32);
        float4 A2 = *(const float4*)(ap + 64);
        float4 A3 = *(const float4*)(ap + 96);
        float4 Bv0 = *(const float4*)(bp);
        float4 Bv1 = *(const float4*)(bp + 32);
        float4 Bv2 = *(const float4*)(bp + 64);
        float4 Bv3 = *(const float4*)(bp + 96);
        DOT4(acc00, A0, Bv0); DOT4(acc01, A0, Bv1); DOT4(acc02, A0, Bv2); DOT4(acc03, A0, Bv3);
        DOT4(acc10, A1, Bv0); DOT4(acc11, A1, Bv1); DOT4(acc12, A1, Bv2); DOT4(acc13, A1, Bv3);
        DOT4(acc20, A2, Bv0); DOT4(acc21, A2, Bv1); DOT4(acc22, A2, Bv2); DOT4(acc23, A2, Bv3);
        DOT4(acc30, A3, Bv0); DOT4(acc31, A3, Bv1); DOT4(acc32, A3, Bv2); DOT4(acc33, A3, Bv3);
      }
      if (s + 1 < NST) {
        float* aL = smem + q * 2048 + (buf ^ 1) * 1024;
        float* bL = smem + 8192 + q * 4096 + (buf ^ 1) * 2048;
        *(float4*)(aL + sm * 32 + swz(sm, skh))      = sA0;
        *(float4*)(aL + sm * 32 + swz(sm, skh + 4))  = sA1;
        *(float4*)(bL + sn * 32 + swz(sn, snk))      = sB0;
        *(float4*)(bL + sn * 32 + swz(sn, snk + 4))  = sB1;
        *(float4*)(bL + sn * 32 + swz(sn, snk + 8))  = sB2;
        *(float4*)(bL + sn * 32 + swz(sn, snk + 12)) = sB3;
      }
      __syncthreads();
    }
  }
  {
    const int ilo = q * 8;
    const int ihi = (q == 3) ? INq : (ilo + 8);
    const float* xb = x + (size_t)b0 * Tq * INq + (size_t)t * INq;
    const float* wv = Wi2h + (size_t)j0 * INq;
    const size_t xs = (size_t)Tq * INq;
    for (int i = ilo; i < ihi; ++i) {
      float x0 = xb[i], x1 = xb[xs + i], x2 = xb[2 * xs + i], x3 = xb[3 * xs + i];
      float w0 = wv[i], w1 = wv[INq + i], w2 = wv[2 * INq + i], w3 = wv[3 * INq + i];
      acc00 = fmaf(x0, w0, acc00); acc01 = fmaf(x0, w1, acc01);
      acc02 = fmaf(x0, w2, acc02); acc03 = fmaf(x0, w3, acc03);
      acc10 = fmaf(x1, w0, acc10); acc11 = fmaf(x1, w1, acc11);
      acc12 = fmaf(x1, w2, acc12); acc13 = fmaf(x1, w3, acc13);
      acc20 = fmaf(x2, w0, acc20); acc21 = fmaf(x2, w1, acc21);
      acc22 = fmaf(x2, w2, acc22); acc23 = fmaf(x2, w3, acc23);
      acc30 = fmaf(x3, w0, acc30); acc31 = fmaf(x3, w1, acc31);
      acc32 = fmaf(x3, w2, acc32); acc33 = fmaf(x3, w3, acc33);
    }
  }
  if (q != 0) {
    float* rd = smem + (q - 1) * 2560 + qt * 20;
    *(float4*)(rd + 0)  = make_float4(acc00, acc01, acc02, acc03);
    *(float4*)(rd + 4)  = make_float4(acc10, acc11, acc12, acc13);
    *(float4*)(rd + 8)  = make_float4(acc20, acc21, acc22, acc23);
    *(float4*)(rd + 12) = make_float4(acc30, acc31, acc32, acc33);
  }
  __syncthreads();
  if (q == 0) {
#pragma unroll
    for (int p = 0; p < 3; ++p) {
      const float* rd = smem + p * 2560 + qt * 20;
      float4 r0 = *(const float4*)(rd + 0),  r1 = *(const float4*)(rd + 4);
      float4 r2 = *(const float4*)(rd + 8),  r3 = *(const float4*)(rd + 12);
      acc00 += r0.x; acc01 += r0.y; acc02 += r0.z; acc03 += r0.w;
      acc10 += r1.x; acc11 += r1.y; acc12 += r1.z; acc13 += r1.w;
      acc20 += r2.x; acc21 += r2.y; acc22 += r2.z; acc23 += r2.w;
      acc30 += r3.x; acc31 += r3.y; acc32 += r3.z; acc33 += r3.w;
    }
    const float* nzb = noise + ((size_t)t * Bq + b0) * Hq + j0;
    float4 nz0 = *(const float4*)(nzb);
    float4 nz1 = *(const float4*)(nzb + Hq);
    float4 nz2 = *(const float4*)(nzb + 2 * Hq);
    float4 nz3 = *(const float4*)(nzb + 3 * Hq);
    float4 hp0 = make_float4(0.f,0.f,0.f,0.f), hp1 = hp0, hp2 = hp0, hp3 = hp0;
    if (t > 0) {
      hp0 = *(const float4*)(hPrev + (size_t)(b0 + 0) * HSTR + j0);
      hp1 = *(const float4*)(hPrev + (size_t)(b0 + 1) * HSTR + j0);
      hp2 = *(const float4*)(hPrev + (size_t)(b0 + 2) * HSTR + j0);
      hp3 = *(const float4*)(hPrev + (size_t)(b0 + 3) * HSTR + j0);
    }
    float4 o0, o1, o2, o3;
    o0.x = fmaf(fmaxf(acc00 + nz0.x, 0.f), 0.1f, 0.9f * hp0.x);
    o0.y = fmaf(fmaxf(acc01 + nz0.y, 0.f), 0.1f, 0.9f * hp0.y);
    o0.z = fmaf(fmaxf(acc02 + nz0.z, 0.f), 0.1f, 0.9f * hp0.z);
    o0.w = fmaf(fmaxf(acc03 + nz0.w, 0.f), 0.1f, 0.9f * hp0.w);
    o1.x = fmaf(fmaxf(acc10 + nz1.x, 0.f), 0.1f, 0.9f * hp1.x);
    o1.y = fmaf(fmaxf(acc11 + nz1.y, 0.f), 0.1f, 0.9f * hp1.y);
    o1.z = fmaf(fmaxf(acc12 + nz1.z, 0.f), 0.1f, 0.9f * hp1.z);
    o1.w = fmaf(fmaxf(acc13 + nz1.w, 0.f), 0.1f, 0.9f * hp1.w);
    o2.x = fmaf(fmaxf(acc20 + nz2.x, 0.f), 0.1f, 0.9f * hp2.x);
    o2.y = fmaf(fmaxf(acc21 + nz2.y, 0.f), 0.1f, 0.9f * hp2.y);
    o2.z = fmaf(fmaxf(acc22 + nz2.z, 0.f), 0.1f, 0.9f * hp2.z);
    o2.w = fmaf(fmaxf(acc23 + nz2.w, 0.f), 0.1f, 0.9f * hp2.w);
    o3.x = fmaf(fmaxf(acc30 + nz3.x, 0.f), 0.1f, 0.9f * hp3.x);
    o3.y = fmaf(fmaxf(acc31 + nz3.y, 0.f), 0.1f, 0.9f * hp3.y);
    o3.z = fmaf(fmaxf(acc32 + nz3.z, 0.f), 0.1f, 0.9f * hp3.z);
    o3.w = fmaf(fmaxf(acc33 + nz3.w, 0.f), 0.1f, 0.9f * hp3.w);
    float* oh = out_h + (size_t)b0 * Tq * Hq + (size_t)t * Hq + j0;
    *(float4*)(oh)                       = o0;
    *(float4*)(oh + (size_t)Tq * Hq)     = o1;
    *(float4*)(oh + (size_t)2 * Tq * Hq) = o2;
    *(float4*)(oh + (size_t)3 * Tq * Hq) = o3;
    if (SLAB) {
      float* sl = slabT + (size_t)b0 * Hq + j0;
      *(float4*)(sl)            = o0;
      *(float4*)(sl + Hq)       = o1;
      *(float4*)(sl + 2 * Hq)   = o2;
      *(float4*)(sl + 3 * Hq)   = o3;
    }
  }
}

extern "C" void kernel_launch(void* const* d_in, const int* in_sizes, int n_in,
                              void* d_out, int out_size, void* d_ws, size_t ws_size,
                              hipStream_t stream) {
  const float* x     = (const float*)d_in[0];
  const float* noise = (const float*)d_in[1];
  const float* Wi2h  = (const float*)d_in[2];
  const float* Wrec  = (const float*)d_in[3];
  const float* Wh2o  = (const float*)d_in[4];
  float* out_h = (float*)d_out;
  float* out_o = out_h + (size_t)Bq * Tq * Hq;

  if (ws_size >= WS_TOTAL) {
    char* ws = (char*)d_ws;
    unsigned short* w1 = (unsigned short*)(ws + WS_W1);
    unsigned short* w2 = (unsigned short*)(ws + WS_W2);
    unsigned short* w3 = (unsigned short*)(ws + WS_W3);
    float* slab0 = (float*)(ws + WS_SLABF0);
    float* slab1 = (float*)(ws + WS_SLABF1);
    float* WiT   = (float*)(ws + WS_WIT);
    unsigned* bar = (unsigned*)(ws + WS_BAR);
    unsigned short* ap[2][3];
    for (int pp = 0; pp < 2; ++pp)
      for (int p = 0; p < 3; ++p)
        ap[pp][p] = (unsigned short*)(ws + WS_APARTS + ((size_t)(pp * 3 + p)) * 1048576ull);

    conv_wrec<<<1024, 256, 0, stream>>>(Wrec, w1, w2, w3);
    conv_wi<<<(INq * Hq + 255) / 256, 256, 0, stream>>>(Wi2h, WiT, bar);

    void* args[] = { (void*)&x, (void*)&noise, (void*)&WiT, (void*)&Wh2o,
                     (void*)&w1, (void*)&w2, (void*)&w3,
                     (void*)&slab0, (void*)&slab1,
                     (void*)&ap[0][0], (void*)&ap[0][1], (void*)&ap[0][2],
                     (void*)&ap[1][0], (void*)&ap[1][1], (void*)&ap[1][2],
                     (void*)&out_h, (void*)&out_o, (void*)&bar };
    hipError_t err = hipLaunchCooperativeKernel((const void*)rnn_persist,
                                                dim3(256), dim3(512), args, 0, stream);
    (void)err;   // cooperative launch verified working on this harness (R5)
  } else {
    const bool use_ws = ws_size >= (size_t)2 * Bq * Hq * sizeof(float);
    float* slab0 = (float*)d_ws;
    float* slab1 = slab0 + (size_t)Bq * Hq;
    if (use_ws) {
      for (int t = 0; t < Tq; ++t) {
        const float* sp = (t > 0) ? (((t - 1) & 1) ? slab1 : slab0) : nullptr;
        float*       st = (t & 1) ? slab1 : slab0;
        rnn_step<true><<<256, 512, 0, stream>>>(x, noise, Wi2h, Wrec, Wh2o,
                                                out_h, out_o, sp, st, t);
      }
      const float* hb = ((Tq - 1) & 1) ? slab1 : slab0;
      proj_tail<<<4, 256, 0, stream>>>(hb, (size_t)Hq, Wh2o, out_o, Tq - 1);
    } else {
      for (int t = 0; t < Tq; ++t) {
        rnn_step<false><<<256, 512, 0, stream>>>(x, noise, Wi2h, Wrec, Wh2o,
                                                 out_h, out_o, nullptr, nullptr, t);
      }
      proj_tail<<<4, 256, 0, stream>>>(out_h + (size_t)(Tq - 1) * Hq,
                                       (size_t)Tq * Hq, Wh2o, out_o, Tq - 1);
    }
  }
}

// Round 17
// 8078.479 us; speedup vs baseline: 3.3602x; 3.3602x over previous
//
#include <hip/hip_runtime.h>
#include <math.h>

#define Bq 256
#define Tq 200
#define INq 33
#define Hq 2048
#define OUTq 4

typedef __attribute__((ext_vector_type(8))) short bf16x8;
typedef __attribute__((ext_vector_type(16))) float f32x16;
typedef __attribute__((ext_vector_type(4))) unsigned short us4;

#define MFMA32(A, B, C) __builtin_amdgcn_mfma_f32_32x32x16_bf16((A), (B), (C), 0, 0, 0)

__device__ __forceinline__ unsigned short f32_to_bf16(float f) {
  unsigned u = __float_as_uint(f);
  unsigned r = 0x7FFFu + ((u >> 16) & 1u);
  return (unsigned short)((u + r) >> 16);
}
__device__ __forceinline__ float bf16_to_f32(unsigned short h) {
  return __uint_as_float((unsigned)h << 16);
}

// ws byte offsets
#define WS_W1     0ull
#define WS_W2     8388608ull
#define WS_W3     16777216ull
#define WS_SLABF0 25165824ull
#define WS_SLABF1 27262976ull
#define WS_APARTS 29360128ull           // ap[pp][part] = + (pp*3+part)*1048576
#define WS_WIT    35651584ull           // WiT [33][2048] f32
#define WS_TOTAL  35921920ull

#define DOT4(ACC, Av, Bv) \
  ACC = fmaf((Av).x, (Bv).x, ACC); ACC = fmaf((Av).y, (Bv).y, ACC); \
  ACC = fmaf((Av).z, (Bv).z, ACC); ACC = fmaf((Av).w, (Bv).w, ACC)

// ---------------------------------------------------------------------------
// Pack Wrec -> 3 bf16 parts in MFMA-fragment order (verified R11-R15)
// ---------------------------------------------------------------------------
__global__ __launch_bounds__(256) void conv_wrec(
    const float* __restrict__ W, unsigned short* __restrict__ w1,
    unsigned short* __restrict__ w2, unsigned short* __restrict__ w3)
{
  const int g   = blockIdx.x * 256 + threadIdx.x;
  const int col = g >> 7;
  const int kc  = g & 127;
  const float* src = W + (size_t)col * Hq + kc * 16;
  unsigned short s1[16], s2[16], s3[16];
#pragma unroll
  for (int j = 0; j < 16; ++j) {
    float v = src[j];
    unsigned short b1 = f32_to_bf16(v);
    float r1 = v - bf16_to_f32(b1);
    unsigned short b2 = f32_to_bf16(r1);
    float r2 = r1 - bf16_to_f32(b2);
    s1[j] = b1; s2[j] = b2; s3[j] = f32_to_bf16(r2);
  }
  const size_t o_lo = ((size_t)(kc * 64 + (col >> 5)) * 64 + (col & 31)) * 8;
  const size_t o_hi = o_lo + 256;
#pragma unroll
  for (int jj = 0; jj < 2; ++jj) {
    *(us4*)&w1[o_lo + jj * 4] = *(us4*)&s1[jj * 4];
    *(us4*)&w1[o_hi + jj * 4] = *(us4*)&s1[8 + jj * 4];
    *(us4*)&w2[o_lo + jj * 4] = *(us4*)&s2[jj * 4];
    *(us4*)&w2[o_hi + jj * 4] = *(us4*)&s2[8 + jj * 4];
    *(us4*)&w3[o_lo + jj * 4] = *(us4*)&s3[jj * 4];
    *(us4*)&w3[o_hi + jj * 4] = *(us4*)&s3[8 + jj * 4];
  }
}

// Wi2h [2048][33] -> WiT [33][2048]
__global__ __launch_bounds__(256) void conv_wi(
    const float* __restrict__ Wi2h, float* __restrict__ WiT)
{
  const int g = blockIdx.x * 256 + threadIdx.x;
  if (g >= INq * Hq) return;
  const int i = g >> 11;
  const int c = g & 2047;
  WiT[(size_t)i * Hq + c] = Wi2h[(size_t)c * INq + i];
}

// ---------------------------------------------------------------------------
// tail softmax head
// ---------------------------------------------------------------------------
__global__ __launch_bounds__(256) void proj_tail(
    const float* __restrict__ hbase, size_t rstride,
    const float* __restrict__ Wh2o, float* __restrict__ out_o, int tp)
{
  const int tid = threadIdx.x;
  const int r  = blockIdx.x * 64 + (tid >> 2);
  const int p4 = tid & 3;
  const float* hp = hbase + (size_t)r * rstride;
  float a0 = 0.f, a1 = 0.f, a2 = 0.f, a3 = 0.f;
  const int k0 = p4 * 512;
#pragma unroll 4
  for (int k = k0; k < k0 + 512; k += 4) {
    float4 hv = *(const float4*)(hp + k);
    float4 w0 = *(const float4*)(Wh2o + 0 * Hq + k);
    float4 w1 = *(const float4*)(Wh2o + 1 * Hq + k);
    float4 w2 = *(const float4*)(Wh2o + 2 * Hq + k);
    float4 w3 = *(const float4*)(Wh2o + 3 * Hq + k);
    DOT4(a0, hv, w0); DOT4(a1, hv, w1); DOT4(a2, hv, w2); DOT4(a3, hv, w3);
  }
  a0 += __shfl_xor(a0, 1); a1 += __shfl_xor(a1, 1);
  a2 += __shfl_xor(a2, 1); a3 += __shfl_xor(a3, 1);
  a0 += __shfl_xor(a0, 2); a1 += __shfl_xor(a1, 2);
  a2 += __shfl_xor(a2, 2); a3 += __shfl_xor(a3, 2);
  if (p4 == 0) {
    float m  = fmaxf(fmaxf(a0, a1), fmaxf(a2, a3));
    float e0 = expf(a0 - m), e1 = expf(a1 - m);
    float e2 = expf(a2 - m), e3 = expf(a3 - m);
    float inv = 1.0f / (e0 + e1 + e2 + e3);
    float* op = out_o + ((size_t)r * Tq + tp) * OUTq;
    op[0] = e0 * inv; op[1] = e1 * inv; op[2] = e2 * inv; op[3] = e3 * inv;
  }
}

// ---------------------------------------------------------------------------
// MFMA step: 512 WGs x 512 thr (2 WGs/CU, 4 waves/SIMD). WG = (TR,TC,ct)
// 32x32 tile; 8 waves split K 8-way (16 chunks each). 8-product 3-way-split
// (R11 numerics). Fragment loads for the first two granules are issued
// BEFORE the softmax-head phase so the head (~3us) hides the L3 cold-start
// latency of the pipeline. Fixed-order 8-partial combine -> deterministic.
// ---------------------------------------------------------------------------
__global__ __launch_bounds__(512, 4) void rnn_step_mfma(
    const float* __restrict__ x, const float* __restrict__ noise,
    const float* __restrict__ WiT, const float* __restrict__ Wh2o,
    const unsigned short* __restrict__ w1, const unsigned short* __restrict__ w2,
    const unsigned short* __restrict__ w3,
    const float* __restrict__ hprevF,
    const unsigned short* __restrict__ a1, const unsigned short* __restrict__ a2,
    const unsigned short* __restrict__ a3,
    float* __restrict__ houtF,
    unsigned short* __restrict__ o1, unsigned short* __restrict__ o2,
    unsigned short* __restrict__ o3,
    float* __restrict__ out_h, float* __restrict__ out_o, int t)
{
  __shared__ float P[8 * 1152 + 32];   // [8 q][32 row][36] + head scratch

  const int wg  = blockIdx.x;
  const int tid = threadIdx.x;

  // XCD-chunked swizzle: XCD c owns wgs [64c,64c+64) = col-tiles [4c,4c+4)
  const int L  = (wg & 7) * 64 + (wg >> 3);
  const int TC = L >> 4;          // 0..31
  const int TR = (L >> 1) & 7;    // 0..7
  const int ct = L & 1;

  const int lane = tid & 63;
  const int q    = __builtin_amdgcn_readfirstlane(tid >> 6);   // 0..7

  // ---- fragment pointers + PRE-ISSUED loads (before head: latency hidden) --
  const int kc0 = q * 16;
  const unsigned short* pa1 = a1 + ((size_t)(kc0 * 8 + TR) * 64 + lane) * 8;
  const unsigned short* pa2 = a2 + ((size_t)(kc0 * 8 + TR) * 64 + lane) * 8;
  const unsigned short* pa3 = a3 + ((size_t)(kc0 * 8 + TR) * 64 + lane) * 8;
  const int cb = TC * 2 + ct;
  const unsigned short* pb1 = w1 + ((size_t)(kc0 * 64 + cb) * 64 + lane) * 8;
  const unsigned short* pb2 = w2 + ((size_t)(kc0 * 64 + cb) * 64 + lane) * 8;
  const unsigned short* pb3 = w3 + ((size_t)(kc0 * 64 + cb) * 64 + lane) * 8;

#define LA(P_, c) (*(const bf16x8*)((P_) + ((size_t)(c) << 12)))
#define LB(P_, c) (*(const bf16x8*)((P_) + ((size_t)(c) << 15)))
  bf16x8 A1x, A2x, A3x, B1x, B2x, B3x;
  bf16x8 A1y, A2y, A3y, B1y, B2y, B3y;
  if (t > 0) {
    A1x = LA(pa1, 0); A2x = LA(pa2, 0); A3x = LA(pa3, 0);
    B1x = LB(pb1, 0); B2x = LB(pb2, 0); B3x = LB(pb3, 0);
    A1y = LA(pa1, 1); A2y = LA(pa2, 1); A3y = LA(pa3, 1);
    B1y = LB(pb1, 1); B2y = LB(pb2, 1); B3y = LB(pb3, 1);
  }

  // ---- softmax head for step t-1 (ct==0 WGs only; row = TC*8+TR) ----
  if (t > 0 && ct == 0) {
    float* ps = P + 8 * 1152;
    const int r  = TC * 8 + TR;
    const int i4 = tid * 4;
    float4 hv  = *(const float4*)(hprevF + (size_t)r * Hq + i4);
    float4 q0v = *(const float4*)(Wh2o + 0 * Hq + i4);
    float4 q1v = *(const float4*)(Wh2o + 1 * Hq + i4);
    float4 q2v = *(const float4*)(Wh2o + 2 * Hq + i4);
    float4 q3v = *(const float4*)(Wh2o + 3 * Hq + i4);
    float s0 = 0.f, s1 = 0.f, s2 = 0.f, s3 = 0.f;
    DOT4(s0, hv, q0v); DOT4(s1, hv, q1v); DOT4(s2, hv, q2v); DOT4(s3, hv, q3v);
#pragma unroll
    for (int m = 1; m <= 32; m <<= 1) {
      s0 += __shfl_xor(s0, m); s1 += __shfl_xor(s1, m);
      s2 += __shfl_xor(s2, m); s3 += __shfl_xor(s3, m);
    }
    if ((tid & 63) == 0) {
      ps[q * 4 + 0] = s0; ps[q * 4 + 1] = s1;
      ps[q * 4 + 2] = s2; ps[q * 4 + 3] = s3;
    }
    __syncthreads();
    if (tid == 0) {
      float t0 = 0.f, t1 = 0.f, t2 = 0.f, t3 = 0.f;
#pragma unroll
      for (int w = 0; w < 8; ++w) {   // fixed order
        t0 += ps[w * 4 + 0]; t1 += ps[w * 4 + 1];
        t2 += ps[w * 4 + 2]; t3 += ps[w * 4 + 3];
      }
      float m  = fmaxf(fmaxf(t0, t1), fmaxf(t2, t3));
      float e0 = expf(t0 - m), e1 = expf(t1 - m);
      float e2 = expf(t2 - m), e3 = expf(t3 - m);
      float inv = 1.0f / (e0 + e1 + e2 + e3);
      float* op = out_o + ((size_t)r * Tq + (t - 1)) * OUTq;
      op[0] = e0 * inv; op[1] = e1 * inv; op[2] = e2 * inv; op[3] = e3 * inv;
    }
    __syncthreads();
  }

  f32x16 accA, accB;
#pragma unroll
  for (int i = 0; i < 16; ++i) { accA[i] = 0.f; accB[i] = 0.f; }

  if (t > 0) {
    // 8-product split (R11 numerics: only a3*b3 dropped, ~2^-36)
    for (int s = 0; s < 16; s += 2) {
      accA = MFMA32(A1x, B1x, accA);  accB = MFMA32(A2x, B1x, accB);
      accB = MFMA32(A1x, B2x, accB);  accA = MFMA32(A2x, B2x, accA);
      accA = MFMA32(A3x, B1x, accA);  accB = MFMA32(A1x, B3x, accB);
      accB = MFMA32(A3x, B2x, accB);  accA = MFMA32(A2x, B3x, accA);
      if (s + 2 < 16) {
        A1x = LA(pa1, s + 2); A2x = LA(pa2, s + 2); A3x = LA(pa3, s + 2);
        B1x = LB(pb1, s + 2); B2x = LB(pb2, s + 2); B3x = LB(pb3, s + 2);
      }
      accA = MFMA32(A1y, B1y, accA);  accB = MFMA32(A2y, B1y, accB);
      accB = MFMA32(A1y, B2y, accB);  accA = MFMA32(A2y, B2y, accA);
      accA = MFMA32(A3y, B1y, accA);  accB = MFMA32(A1y, B3y, accB);
      accB = MFMA32(A3y, B2y, accB);  accA = MFMA32(A2y, B3y, accA);
      if (s + 3 < 16) {
        A1y = LA(pa1, s + 3); A2y = LA(pa2, s + 3); A3y = LA(pa3, s + 3);
        B1y = LB(pb1, s + 3); B2y = LB(pb2, s + 3); B3y = LB(pb3, s + 3);
      }
    }
#undef LA
#undef LB

    // partial -> LDS P[q][row][36]
    const int prow0 = (lane >> 5) * 4;
    float* pw = P + q * 1152 + (lane & 31);
#pragma unroll
    for (int rr = 0; rr < 16; ++rr) {
      const int row = prow0 + (rr & 3) + 8 * (rr >> 2);
      pw[row * 36] = accA[rr] + accB[rr];
    }
  }
  __syncthreads();

  // ---- epilogue: first 256 threads, thread -> (row, 4 cols) ----
  if (tid < 256) {
    const int row = tid >> 3;          // 0..31
    const int j0l = (tid & 7) * 4;     // 0..28
    const int b   = TR * 32 + row;
    const int gc  = TC * 64 + ct * 32 + j0l;

    float e0 = 0.f, e1 = 0.f, e2 = 0.f, e3 = 0.f;
    if (t > 0) {
#pragma unroll
      for (int qq = 0; qq < 8; ++qq) { // fixed order
        const float* pr = P + qq * 1152 + row * 36 + j0l;
        float4 pv = *(const float4*)pr;
        e0 += pv.x; e1 += pv.y; e2 += pv.z; e3 += pv.w;
      }
    }

    // x-projection (WiT rows L1/L2-hot)
    const float* xb = x + ((size_t)b * Tq + t) * INq;
#pragma unroll
    for (int i = 0; i < INq; ++i) {
      float xv = xb[i];
      float4 wv4 = *(const float4*)(WiT + (size_t)i * Hq + gc);
      e0 = fmaf(xv, wv4.x, e0); e1 = fmaf(xv, wv4.y, e1);
      e2 = fmaf(xv, wv4.z, e2); e3 = fmaf(xv, wv4.w, e3);
    }

    float4 nz = *(const float4*)(noise + ((size_t)t * Bq + b) * Hq + gc);
    e0 += nz.x; e1 += nz.y; e2 += nz.z; e3 += nz.w;

    float4 hp = make_float4(0.f, 0.f, 0.f, 0.f);
    if (t > 0) hp = *(const float4*)(hprevF + (size_t)b * Hq + gc);

    float4 o;
    o.x = fmaf(fmaxf(e0, 0.f), 0.1f, 0.9f * hp.x);
    o.y = fmaf(fmaxf(e1, 0.f), 0.1f, 0.9f * hp.y);
    o.z = fmaf(fmaxf(e2, 0.f), 0.1f, 0.9f * hp.z);
    o.w = fmaf(fmaxf(e3, 0.f), 0.1f, 0.9f * hp.w);

    *(float4*)(out_h + ((size_t)b * Tq + t) * Hq + gc) = o;
    *(float4*)(houtF + (size_t)b * Hq + gc) = o;

    us4 p1v, p2v, p3v;
    float ov[4] = { o.x, o.y, o.z, o.w };
#pragma unroll
    for (int c = 0; c < 4; ++c) {
      unsigned short b1 = f32_to_bf16(ov[c]);
      float r1 = ov[c] - bf16_to_f32(b1);
      unsigned short b2 = f32_to_bf16(r1);
      float r2 = r1 - bf16_to_f32(b2);
      p1v[c] = b1; p2v[c] = b2; p3v[c] = f32_to_bf16(r2);
    }
    const size_t apo = ((size_t)((gc >> 4) * 8 + TR) * 64
                        + ((gc >> 3) & 1) * 32 + row) * 8 + (gc & 7);
    *(us4*)&o1[apo] = p1v;
    *(us4*)&o2[apo] = p2v;
    *(us4*)&o3[apo] = p3v;
  }
}

// ===========================================================================
// Fallback (R9 f32 path) if workspace too small.
// ===========================================================================
#define BKq 32
#define NST 16
__device__ __forceinline__ int swz(int row, int k) {
  return k ^ (((row >> 2) & 7) << 2);
}

template<bool SLAB>
__global__ __launch_bounds__(512, 2) void rnn_step(
    const float* __restrict__ x, const float* __restrict__ noise,
    const float* __restrict__ Wi2h, const float* __restrict__ Wrec,
    const float* __restrict__ Wh2o, float* __restrict__ out_h,
    float* __restrict__ out_o, const float* __restrict__ slabP,
    float* __restrict__ slabT, int t)
{
  constexpr size_t HSTR = SLAB ? (size_t)Hq : (size_t)Tq * Hq;
  __shared__ float smem[24576];
  const int wg  = blockIdx.x;
  const int tid = threadIdx.x;
  const int L  = (wg & 7) * 32 + (wg >> 3);
  const int TC = L >> 3;
  const int TR = L & 7;
  const int q  = tid >> 7;
  const int qt = tid & 127;
  const int tx = qt & 15;
  const int ty = qt >> 4;
  const int m0 = ty * 4, n0 = tx * 4;
  const int b0 = TR * 32 + m0;
  const int j0 = TC * 64 + n0;
  const int kb = q * 512;
  const float* hPrev = SLAB ? slabP : (out_h + (size_t)(t > 0 ? t - 1 : 0) * Hq);
  const int sm  = ((qt & 7) << 2) | ((qt >> 3) & 3);
  const int skh = ((qt >> 5) & 3) * 8;
  const int sn  = (((qt >> 5) & 1) << 5) | ((qt & 7) << 2) | ((qt >> 3) & 3);
  const int snk = ((qt >> 6) & 1) * 16;
  const float* gA = hPrev + (size_t)(TR * 32 + sm) * HSTR + kb + skh;
  const float* gB = Wrec + (size_t)(TC * 64 + sn) * Hq + kb + snk;
  float4 sA0, sA1, sB0, sB1, sB2, sB3;
  if (t > 0) {
    sA0 = *(const float4*)(gA);      sA1 = *(const float4*)(gA + 4);
    sB0 = *(const float4*)(gB);      sB1 = *(const float4*)(gB + 4);
    sB2 = *(const float4*)(gB + 8);  sB3 = *(const float4*)(gB + 12);
  }
  if (t > 0) {
    const int i4 = tid * 4;
    float4 hv = *(const float4*)(hPrev + (size_t)wg * HSTR + i4);
    float4 w0 = *(const float4*)(Wh2o + 0 * Hq + i4);
    float4 w1 = *(const float4*)(Wh2o + 1 * Hq + i4);
    float4 w2 = *(const float4*)(Wh2o + 2 * Hq + i4);
    float4 w3 = *(const float4*)(Wh2o + 3 * Hq + i4);
    float a0 = 0.f, a1 = 0.f, a2 = 0.f, a3 = 0.f;
    DOT4(a0, hv, w0); DOT4(a1, hv, w1); DOT4(a2, hv, w2); DOT4(a3, hv, w3);
#pragma unroll
    for (int m = 1; m <= 32; m <<= 1) {
      a0 += __shfl_xor(a0, m); a1 += __shfl_xor(a1, m);
      a2 += __shfl_xor(a2, m); a3 += __shfl_xor(a3, m);
    }
    if ((tid & 63) == 0) {
      const int w = tid >> 6;
      smem[w * 4 + 0] = a0; smem[w * 4 + 1] = a1;
      smem[w * 4 + 2] = a2; smem[w * 4 + 3] = a3;
    }
    __syncthreads();
    if (tid == 0) {
      float s0 = 0.f, s1 = 0.f, s2 = 0.f, s3 = 0.f;
#pragma unroll
      for (int w = 0; w < 8; ++w) {
        s0 += smem[w * 4 + 0]; s1 += smem[w * 4 + 1];
        s2 += smem[w * 4 + 2]; s3 += smem[w * 4 + 3];
      }
      float m  = fmaxf(fmaxf(s0, s1), fmaxf(s2, s3));
      float e0 = expf(s0 - m), e1 = expf(s1 - m);
      float e2 = expf(s2 - m), e3 = expf(s3 - m);
      float inv = 1.0f / (e0 + e1 + e2 + e3);
      float* op = out_o + ((size_t)wg * Tq + (t - 1)) * OUTq;
      op[0] = e0 * inv; op[1] = e1 * inv; op[2] = e2 * inv; op[3] = e3 * inv;
    }
    __syncthreads();
  }
  float acc00 = 0.f, acc01 = 0.f, acc02 = 0.f, acc03 = 0.f;
  float acc10 = 0.f, acc11 = 0.f, acc12 = 0.f, acc13 = 0.f;
  float acc20 = 0.f, acc21 = 0.f, acc22 = 0.f, acc23 = 0.f;
  float acc30 = 0.f, acc31 = 0.f, acc32 = 0.f, acc33 = 0.f;
  if (t > 0) {
    {
      float* aL = smem + q * 2048;
      float* bL = smem + 8192 + q * 4096;
      *(float4*)(aL + sm * 32 + swz(sm, skh))      = sA0;
      *(float4*)(aL + sm * 32 + swz(sm, skh + 4))  = sA1;
      *(float4*)(bL + sn * 32 + swz(sn, snk))      = sB0;
      *(float4*)(bL + sn * 32 + swz(sn, snk + 4))  = sB1;
      *(float4*)(bL + sn * 32 + swz(sn, snk + 8))  = sB2;
      *(float4*)(bL + sn * 32 + swz(sn, snk + 12)) = sB3;
    }
    __syncthreads();
    const int aKey = ty << 2;
    const int bKey = (tx & 7) << 2;
    for (int s = 0; s < NST; ++s) {
      const int buf = s & 1;
      if (s + 1 < NST) {
        const int o = (s + 1) * BKq;
        sA0 = *(const float4*)(gA + o);      sA1 = *(const float4*)(gA + o + 4);
        sB0 = *(const float4*)(gB + o);      sB1 = *(const float4*)(gB + o + 4);
        sB2 = *(const float4*)(gB + o + 8);  sB3 = *(const float4*)(gB + o + 12);
      }
      const float* aT = smem + q * 2048 + buf * 1024 + ty * 128;
      const float* bT = smem + 8192 + q * 4096 + buf * 2048 + tx * 128;
#pragma unroll
      for (int k4 = 0; k4 < BKq; k4 += 4) {
        const float* ap = aT + (k4 ^ aKey);
        const float* bp = bT + (k4 ^ bKey);
        float4 A0 = *(const float4*)(ap);
        float4 A1 = *(const float4*)(ap + 32);
        float4 A2 = *(const float4*)(ap + 64);
        float4 A3 = *(const float4*)(ap + 96);
        float4 Bv0 = *(const float4*)(bp);
        float4 Bv1 = *(const float4*)(bp + 32);
        float4 Bv2 = *(const float4*)(bp + 64);
        float4 Bv3 = *(const float4*)(bp + 96);
        DOT4(acc00, A0, Bv0); DOT4(acc01, A0, Bv1); DOT4(acc02, A0, Bv2); DOT4(acc03, A0, Bv3);
        DOT4(acc10, A1, Bv0); DOT4(acc11, A1, Bv1); DOT4(acc12, A1, Bv2); DOT4(acc13, A1, Bv3);
        DOT4(acc20, A2, Bv0); DOT4(acc21, A2, Bv1); DOT4(acc22, A2, Bv2); DOT4(acc23, A2, Bv3);
        DOT4(acc30, A3, Bv0); DOT4(acc31, A3, Bv1); DOT4(acc32, A3, Bv2); DOT4(acc33, A3, Bv3);
      }
      if (s + 1 < NST) {
        float* aL = smem + q * 2048 + (buf ^ 1) * 1024;
        float* bL = smem + 8192 + q * 4096 + (buf ^ 1) * 2048;
        *(float4*)(aL + sm * 32 + swz(sm, skh))      = sA0;
        *(float4*)(aL + sm * 32 + swz(sm, skh + 4))  = sA1;
        *(float4*)(bL + sn * 32 + swz(sn, snk))      = sB0;
        *(float4*)(bL + sn * 32 + swz(sn, snk + 4))  = sB1;
        *(float4*)(bL + sn * 32 + swz(sn, snk + 8))  = sB2;
        *(float4*)(bL + sn * 32 + swz(sn, snk + 12)) = sB3;
      }
      __syncthreads();
    }
  }
  {
    const int ilo = q * 8;
    const int ihi = (q == 3) ? INq : (ilo + 8);
    const float* xb = x + (size_t)b0 * Tq * INq + (size_t)t * INq;
    const float* wv = Wi2h + (size_t)j0 * INq;
    const size_t xs = (size_t)Tq * INq;
    for (int i = ilo; i < ihi; ++i) {
      float x0 = xb[i], x1 = xb[xs + i], x2 = xb[2 * xs + i], x3 = xb[3 * xs + i];
      float w0 = wv[i], w1 = wv[INq + i], w2 = wv[2 * INq + i], w3 = wv[3 * INq + i];
      acc00 = fmaf(x0, w0, acc00); acc01 = fmaf(x0, w1, acc01);
      acc02 = fmaf(x0, w2, acc02); acc03 = fmaf(x0, w3, acc03);
      acc10 = fmaf(x1, w0, acc10); acc11 = fmaf(x1, w1, acc11);
      acc12 = fmaf(x1, w2, acc12); acc13 = fmaf(x1, w3, acc13);
      acc20 = fmaf(x2, w0, acc20); acc21 = fmaf(x2, w1, acc21);
      acc22 = fmaf(x2, w2, acc22); acc23 = fmaf(x2, w3, acc23);
      acc30 = fmaf(x3, w0, acc30); acc31 = fmaf(x3, w1, acc31);
      acc32 = fmaf(x3, w2, acc32); acc33 = fmaf(x3, w3, acc33);
    }
  }
  if (q != 0) {
    float* rd = smem + (q - 1) * 2560 + qt * 20;
    *(float4*)(rd + 0)  = make_float4(acc00, acc01, acc02, acc03);
    *(float4*)(rd + 4)  = make_float4(acc10, acc11, acc12, acc13);
    *(float4*)(rd + 8)  = make_float4(acc20, acc21, acc22, acc23);
    *(float4*)(rd + 12) = make_float4(acc30, acc31, acc32, acc33);
  }
  __syncthreads();
  if (q == 0) {
#pragma unroll
    for (int p = 0; p < 3; ++p) {
      const float* rd = smem + p * 2560 + qt * 20;
      float4 r0 = *(const float4*)(rd + 0),  r1 = *(const float4*)(rd + 4);
      float4 r2 = *(const float4*)(rd + 8),  r3 = *(const float4*)(rd + 12);
      acc00 += r0.x; acc01 += r0.y; acc02 += r0.z; acc03 += r0.w;
      acc10 += r1.x; acc11 += r1.y; acc12 += r1.z; acc13 += r1.w;
      acc20 += r2.x; acc21 += r2.y; acc22 += r2.z; acc23 += r2.w;
      acc30 += r3.x; acc31 += r3.y; acc32 += r3.z; acc33 += r3.w;
    }
    const float* nzb = noise + ((size_t)t * Bq + b0) * Hq + j0;
    float4 nz0 = *(const float4*)(nzb);
    float4 nz1 = *(const float4*)(nzb + Hq);
    float4 nz2 = *(const float4*)(nzb + 2 * Hq);
    float4 nz3 = *(const float4*)(nzb + 3 * Hq);
    float4 hp0 = make_float4(0.f,0.f,0.f,0.f), hp1 = hp0, hp2 = hp0, hp3 = hp0;
    if (t > 0) {
      hp0 = *(const float4*)(hPrev + (size_t)(b0 + 0) * HSTR + j0);
      hp1 = *(const float4*)(hPrev + (size_t)(b0 + 1) * HSTR + j0);
      hp2 = *(const float4*)(hPrev + (size_t)(b0 + 2) * HSTR + j0);
      hp3 = *(const float4*)(hPrev + (size_t)(b0 + 3) * HSTR + j0);
    }
    float4 o0, o1, o2, o3;
    o0.x = fmaf(fmaxf(acc00 + nz0.x, 0.f), 0.1f, 0.9f * hp0.x);
    o0.y = fmaf(fmaxf(acc01 + nz0.y, 0.f), 0.1f, 0.9f * hp0.y);
    o0.z = fmaf(fmaxf(acc02 + nz0.z, 0.f), 0.1f, 0.9f * hp0.z);
    o0.w = fmaf(fmaxf(acc03 + nz0.w, 0.f), 0.1f, 0.9f * hp0.w);
    o1.x = fmaf(fmaxf(acc10 + nz1.x, 0.f), 0.1f, 0.9f * hp1.x);
    o1.y = fmaf(fmaxf(acc11 + nz1.y, 0.f), 0.1f, 0.9f * hp1.y);
    o1.z = fmaf(fmaxf(acc12 + nz1.z, 0.f), 0.1f, 0.9f * hp1.z);
    o1.w = fmaf(fmaxf(acc13 + nz1.w, 0.f), 0.1f, 0.9f * hp1.w);
    o2.x = fmaf(fmaxf(acc20 + nz2.x, 0.f), 0.1f, 0.9f * hp2.x);
    o2.y = fmaf(fmaxf(acc21 + nz2.y, 0.f), 0.1f, 0.9f * hp2.y);
    o2.z = fmaf(fmaxf(acc22 + nz2.z, 0.f), 0.1f, 0.9f * hp2.z);
    o2.w = fmaf(fmaxf(acc23 + nz2.w, 0.f), 0.1f, 0.9f * hp2.w);
    o3.x = fmaf(fmaxf(acc30 + nz3.x, 0.f), 0.1f, 0.9f * hp3.x);
    o3.y = fmaf(fmaxf(acc31 + nz3.y, 0.f), 0.1f, 0.9f * hp3.y);
    o3.z = fmaf(fmaxf(acc32 + nz3.z, 0.f), 0.1f, 0.9f * hp3.z);
    o3.w = fmaf(fmaxf(acc33 + nz3.w, 0.f), 0.1f, 0.9f * hp3.w);
    float* oh = out_h + (size_t)b0 * Tq * Hq + (size_t)t * Hq + j0;
    *(float4*)(oh)                       = o0;
    *(float4*)(oh + (size_t)Tq * Hq)     = o1;
    *(float4*)(oh + (size_t)2 * Tq * Hq) = o2;
    *(float4*)(oh + (size_t)3 * Tq * Hq) = o3;
    if (SLAB) {
      float* sl = slabT + (size_t)b0 * Hq + j0;
      *(float4*)(sl)            = o0;
      *(float4*)(sl + Hq)       = o1;
      *(float4*)(sl + 2 * Hq)   = o2;
      *(float4*)(sl + 3 * Hq)   = o3;
    }
  }
}

extern "C" void kernel_launch(void* const* d_in, const int* in_sizes, int n_in,
                              void* d_out, int out_size, void* d_ws, size_t ws_size,
                              hipStream_t stream) {
  const float* x     = (const float*)d_in[0];
  const float* noise = (const float*)d_in[1];
  const float* Wi2h  = (const float*)d_in[2];
  const float* Wrec  = (const float*)d_in[3];
  const float* Wh2o  = (const float*)d_in[4];
  float* out_h = (float*)d_out;
  float* out_o = out_h + (size_t)Bq * Tq * Hq;

  if (ws_size >= WS_TOTAL) {
    char* ws = (char*)d_ws;
    unsigned short* w1 = (unsigned short*)(ws + WS_W1);
    unsigned short* w2 = (unsigned short*)(ws + WS_W2);
    unsigned short* w3 = (unsigned short*)(ws + WS_W3);
    float* slabF[2] = { (float*)(ws + WS_SLABF0), (float*)(ws + WS_SLABF1) };
    float* WiT = (float*)(ws + WS_WIT);
    unsigned short* ap[2][3];
    for (int pp = 0; pp < 2; ++pp)
      for (int p = 0; p < 3; ++p)
        ap[pp][p] = (unsigned short*)(ws + WS_APARTS + ((size_t)(pp * 3 + p)) * 1048576ull);

    conv_wrec<<<1024, 256, 0, stream>>>(Wrec, w1, w2, w3);
    conv_wi<<<(INq * Hq + 255) / 256, 256, 0, stream>>>(Wi2h, WiT);

    for (int t = 0; t < Tq; ++t) {
      const int pc = t & 1, pp = pc ^ 1;
      rnn_step_mfma<<<512, 512, 0, stream>>>(
          x, noise, WiT, Wh2o, w1, w2, w3,
          slabF[pp], ap[pp][0], ap[pp][1], ap[pp][2],
          slabF[pc], ap[pc][0], ap[pc][1], ap[pc][2],
          out_h, out_o, t);
    }
    proj_tail<<<4, 256, 0, stream>>>(slabF[(Tq - 1) & 1], (size_t)Hq,
                                     Wh2o, out_o, Tq - 1);
  } else {
    const bool use_ws = ws_size >= (size_t)2 * Bq * Hq * sizeof(float);
    float* slab0 = (float*)d_ws;
    float* slab1 = slab0 + (size_t)Bq * Hq;
    if (use_ws) {
      for (int t = 0; t < Tq; ++t) {
        const float* sp = (t > 0) ? (((t - 1) & 1) ? slab1 : slab0) : nullptr;
        float*       st = (t & 1) ? slab1 : slab0;
        rnn_step<true><<<256, 512, 0, stream>>>(x, noise, Wi2h, Wrec, Wh2o,
                                                out_h, out_o, sp, st, t);
      }
      const float* hb = ((Tq - 1) & 1) ? slab1 : slab0;
      proj_tail<<<4, 256, 0, stream>>>(hb, (size_t)Hq, Wh2o, out_o, Tq - 1);
    } else {
      for (int t = 0; t < Tq; ++t) {
        rnn_step<false><<<256, 512, 0, stream>>>(x, noise, Wi2h, Wrec, Wh2o,
                                                 out_h, out_o, nullptr, nullptr, t);
      }
      proj_tail<<<4, 256, 0, stream>>>(out_h + (size_t)(Tq - 1) * Hq,
                                       (size_t)Tq * Hq, Wh2o, out_o, Tq - 1);
    }
  }
}

// Round 18
// 6282.574 us; speedup vs baseline: 4.3207x; 1.2859x over previous
//
#include <hip/hip_runtime.h>
#include <math.h>

#define Bq 256
#define Tq 200
#define INq 33
#define Hq 2048
#define OUTq 4

typedef __attribute__((ext_vector_type(8))) short bf16x8;
typedef __attribute__((ext_vector_type(16))) float f32x16;
typedef __attribute__((ext_vector_type(4))) unsigned short us4;

#define MFMA32(A, B, C) __builtin_amdgcn_mfma_f32_32x32x16_bf16((A), (B), (C), 0, 0, 0)

__device__ __forceinline__ unsigned short f32_to_bf16(float f) {
  unsigned u = __float_as_uint(f);
  unsigned r = 0x7FFFu + ((u >> 16) & 1u);
  return (unsigned short)((u + r) >> 16);
}
__device__ __forceinline__ float bf16_to_f32(unsigned short h) {
  return __uint_as_float((unsigned)h << 16);
}

// ws byte offsets
#define WS_W1     0ull
#define WS_W2     8388608ull
#define WS_W3     16777216ull
#define WS_SLABF0 25165824ull
#define WS_SLABF1 27262976ull
#define WS_APARTS 29360128ull           // ap[pp][part] = + (pp*3+part)*1048576
#define WS_WIT    35651584ull           // WiT [33][2048] f32
#define WS_TOTAL  35921920ull

#define DOT4(ACC, Av, Bv) \
  ACC = fmaf((Av).x, (Bv).x, ACC); ACC = fmaf((Av).y, (Bv).y, ACC); \
  ACC = fmaf((Av).z, (Bv).z, ACC); ACC = fmaf((Av).w, (Bv).w, ACC)

// ---------------------------------------------------------------------------
// Pack Wrec -> 3 bf16 parts in MFMA-fragment order (verified R11-R17)
// ---------------------------------------------------------------------------
__global__ __launch_bounds__(256) void conv_wrec(
    const float* __restrict__ W, unsigned short* __restrict__ w1,
    unsigned short* __restrict__ w2, unsigned short* __restrict__ w3)
{
  const int g   = blockIdx.x * 256 + threadIdx.x;
  const int col = g >> 7;
  const int kc  = g & 127;
  const float* src = W + (size_t)col * Hq + kc * 16;
  unsigned short s1[16], s2[16], s3[16];
#pragma unroll
  for (int j = 0; j < 16; ++j) {
    float v = src[j];
    unsigned short b1 = f32_to_bf16(v);
    float r1 = v - bf16_to_f32(b1);
    unsigned short b2 = f32_to_bf16(r1);
    float r2 = r1 - bf16_to_f32(b2);
    s1[j] = b1; s2[j] = b2; s3[j] = f32_to_bf16(r2);
  }
  const size_t o_lo = ((size_t)(kc * 64 + (col >> 5)) * 64 + (col & 31)) * 8;
  const size_t o_hi = o_lo + 256;
#pragma unroll
  for (int jj = 0; jj < 2; ++jj) {
    *(us4*)&w1[o_lo + jj * 4] = *(us4*)&s1[jj * 4];
    *(us4*)&w1[o_hi + jj * 4] = *(us4*)&s1[8 + jj * 4];
    *(us4*)&w2[o_lo + jj * 4] = *(us4*)&s2[jj * 4];
    *(us4*)&w2[o_hi + jj * 4] = *(us4*)&s2[8 + jj * 4];
    *(us4*)&w3[o_lo + jj * 4] = *(us4*)&s3[jj * 4];
    *(us4*)&w3[o_hi + jj * 4] = *(us4*)&s3[8 + jj * 4];
  }
}

// Wi2h [2048][33] -> WiT [33][2048]
__global__ __launch_bounds__(256) void conv_wi(
    const float* __restrict__ Wi2h, float* __restrict__ WiT)
{
  const int g = blockIdx.x * 256 + threadIdx.x;
  if (g >= INq * Hq) return;
  const int i = g >> 11;
  const int c = g & 2047;
  WiT[(size_t)i * Hq + c] = Wi2h[(size_t)c * INq + i];
}

// ---------------------------------------------------------------------------
// tail softmax head
// ---------------------------------------------------------------------------
__global__ __launch_bounds__(256) void proj_tail(
    const float* __restrict__ hbase, size_t rstride,
    const float* __restrict__ Wh2o, float* __restrict__ out_o, int tp)
{
  const int tid = threadIdx.x;
  const int r  = blockIdx.x * 64 + (tid >> 2);
  const int p4 = tid & 3;
  const float* hp = hbase + (size_t)r * rstride;
  float a0 = 0.f, a1 = 0.f, a2 = 0.f, a3 = 0.f;
  const int k0 = p4 * 512;
#pragma unroll 4
  for (int k = k0; k < k0 + 512; k += 4) {
    float4 hv = *(const float4*)(hp + k);
    float4 w0 = *(const float4*)(Wh2o + 0 * Hq + k);
    float4 w1 = *(const float4*)(Wh2o + 1 * Hq + k);
    float4 w2 = *(const float4*)(Wh2o + 2 * Hq + k);
    float4 w3 = *(const float4*)(Wh2o + 3 * Hq + k);
    DOT4(a0, hv, w0); DOT4(a1, hv, w1); DOT4(a2, hv, w2); DOT4(a3, hv, w3);
  }
  a0 += __shfl_xor(a0, 1); a1 += __shfl_xor(a1, 1);
  a2 += __shfl_xor(a2, 1); a3 += __shfl_xor(a3, 1);
  a0 += __shfl_xor(a0, 2); a1 += __shfl_xor(a1, 2);
  a2 += __shfl_xor(a2, 2); a3 += __shfl_xor(a3, 2);
  if (p4 == 0) {
    float m  = fmaxf(fmaxf(a0, a1), fmaxf(a2, a3));
    float e0 = expf(a0 - m), e1 = expf(a1 - m);
    float e2 = expf(a2 - m), e3 = expf(a3 - m);
    float inv = 1.0f / (e0 + e1 + e2 + e3);
    float* op = out_o + ((size_t)r * Tq + tp) * OUTq;
    op[0] = e0 * inv; op[1] = e1 * inv; op[2] = e2 * inv; op[3] = e3 * inv;
  }
}

// ---------------------------------------------------------------------------
// MFMA step (R11 structure, depth-4 granule pipeline).
// 256 WGs x 512 thr (1 WG/CU). Wave wv: ct=wv&1, q=wv>>1 (32 chunks of K=16).
// 8-product 3-way split, R11 accumulation order (absmax canary 0.0078125).
// All 4 pipeline granules pre-issued BEFORE the softmax head -> the head's
// ~3us hides the cold-start L3 latency; in-loop cover doubled vs R11.
// ---------------------------------------------------------------------------
__global__ __launch_bounds__(512, 1) void rnn_step_mfma(
    const float* __restrict__ x, const float* __restrict__ noise,
    const float* __restrict__ WiT, const float* __restrict__ Wh2o,
    const unsigned short* __restrict__ w1, const unsigned short* __restrict__ w2,
    const unsigned short* __restrict__ w3,
    const float* __restrict__ hprevF,
    const unsigned short* __restrict__ a1, const unsigned short* __restrict__ a2,
    const unsigned short* __restrict__ a3,
    float* __restrict__ houtF,
    unsigned short* __restrict__ o1, unsigned short* __restrict__ o2,
    unsigned short* __restrict__ o3,
    float* __restrict__ out_h, float* __restrict__ out_o, int t)
{
  __shared__ float P[4 * 2176 + 32];     // [4 q][32 row][68] + proj scratch

  const int wg  = blockIdx.x;
  const int tid = threadIdx.x;

  const int L  = (wg & 7) * 32 + (wg >> 3);   // XCD c owns col-tiles [4c,4c+4)
  const int TC = L >> 3;
  const int TR = L & 7;

  const int lane = tid & 63;
  const int wv   = __builtin_amdgcn_readfirstlane(tid >> 6);
  const int ct   = wv & 1;
  const int q    = wv >> 1;

  // ---- fragment pointers + PRE-ISSUED depth-4 loads (before head) ----
  const int kc0 = q * 32;
  const unsigned short* pa1 = a1 + ((size_t)(kc0 * 8 + TR) * 64 + lane) * 8;
  const unsigned short* pa2 = a2 + ((size_t)(kc0 * 8 + TR) * 64 + lane) * 8;
  const unsigned short* pa3 = a3 + ((size_t)(kc0 * 8 + TR) * 64 + lane) * 8;
  const int cb = TC * 2 + ct;
  const unsigned short* pb1 = w1 + ((size_t)(kc0 * 64 + cb) * 64 + lane) * 8;
  const unsigned short* pb2 = w2 + ((size_t)(kc0 * 64 + cb) * 64 + lane) * 8;
  const unsigned short* pb3 = w3 + ((size_t)(kc0 * 64 + cb) * 64 + lane) * 8;

#define LA(P_, c) (*(const bf16x8*)((P_) + ((size_t)(c) << 12)))
#define LB(P_, c) (*(const bf16x8*)((P_) + ((size_t)(c) << 15)))
  bf16x8 A1x, A2x, A3x, B1x, B2x, B3x;   // granule s+0
  bf16x8 A1y, A2y, A3y, B1y, B2y, B3y;   // granule s+1
  bf16x8 A1z, A2z, A3z, B1z, B2z, B3z;   // granule s+2
  bf16x8 A1w, A2w, A3w, B1w, B2w, B3w;   // granule s+3
  if (t > 0) {
    A1x = LA(pa1, 0); A2x = LA(pa2, 0); A3x = LA(pa3, 0);
    B1x = LB(pb1, 0); B2x = LB(pb2, 0); B3x = LB(pb3, 0);
    A1y = LA(pa1, 1); A2y = LA(pa2, 1); A3y = LA(pa3, 1);
    B1y = LB(pb1, 1); B2y = LB(pb2, 1); B3y = LB(pb3, 1);
    A1z = LA(pa1, 2); A2z = LA(pa2, 2); A3z = LA(pa3, 2);
    B1z = LB(pb1, 2); B2z = LB(pb2, 2); B3z = LB(pb3, 2);
    A1w = LA(pa1, 3); A2w = LA(pa2, 3); A3w = LA(pa3, 3);
    B1w = LB(pb1, 3); B2w = LB(pb2, 3); B3w = LB(pb3, 3);
  }

  // ---- softmax head for step t-1, batch row wg (all 512 threads) ----
  if (t > 0) {
    float* ps = P + 4 * 2176;
    const int i4 = tid * 4;
    float4 hv  = *(const float4*)(hprevF + (size_t)wg * Hq + i4);
    float4 q0v = *(const float4*)(Wh2o + 0 * Hq + i4);
    float4 q1v = *(const float4*)(Wh2o + 1 * Hq + i4);
    float4 q2v = *(const float4*)(Wh2o + 2 * Hq + i4);
    float4 q3v = *(const float4*)(Wh2o + 3 * Hq + i4);
    float s0 = 0.f, s1 = 0.f, s2 = 0.f, s3 = 0.f;
    DOT4(s0, hv, q0v); DOT4(s1, hv, q1v); DOT4(s2, hv, q2v); DOT4(s3, hv, q3v);
#pragma unroll
    for (int m = 1; m <= 32; m <<= 1) {
      s0 += __shfl_xor(s0, m); s1 += __shfl_xor(s1, m);
      s2 += __shfl_xor(s2, m); s3 += __shfl_xor(s3, m);
    }
    if ((tid & 63) == 0) {
      ps[wv * 4 + 0] = s0; ps[wv * 4 + 1] = s1;
      ps[wv * 4 + 2] = s2; ps[wv * 4 + 3] = s3;
    }
    __syncthreads();
    if (tid == 0) {
      float t0 = 0.f, t1 = 0.f, t2 = 0.f, t3 = 0.f;
#pragma unroll
      for (int w = 0; w < 8; ++w) {   // fixed order
        t0 += ps[w * 4 + 0]; t1 += ps[w * 4 + 1];
        t2 += ps[w * 4 + 2]; t3 += ps[w * 4 + 3];
      }
      float m  = fmaxf(fmaxf(t0, t1), fmaxf(t2, t3));
      float e0 = expf(t0 - m), e1 = expf(t1 - m);
      float e2 = expf(t2 - m), e3 = expf(t3 - m);
      float inv = 1.0f / (e0 + e1 + e2 + e3);
      float* op = out_o + ((size_t)wg * Tq + (t - 1)) * OUTq;
      op[0] = e0 * inv; op[1] = e1 * inv; op[2] = e2 * inv; op[3] = e3 * inv;
    }
    __syncthreads();
  }

  f32x16 accA, accB;
#pragma unroll
  for (int i = 0; i < 16; ++i) { accA[i] = 0.f; accB[i] = 0.f; }

  if (t > 0) {
    // depth-4 rolling pipeline; consume granules in order (R11 order kept)
#define CONSUME(S) \
    accA = MFMA32(A1##S, B1##S, accA);  accB = MFMA32(A2##S, B1##S, accB); \
    accB = MFMA32(A1##S, B2##S, accB);  accA = MFMA32(A2##S, B2##S, accA); \
    accA = MFMA32(A3##S, B1##S, accA);  accB = MFMA32(A1##S, B3##S, accB); \
    accB = MFMA32(A3##S, B2##S, accB);  accA = MFMA32(A2##S, B3##S, accA);
#define RELOAD(S, C) \
    A1##S = LA(pa1, (C)); A2##S = LA(pa2, (C)); A3##S = LA(pa3, (C)); \
    B1##S = LB(pb1, (C)); B2##S = LB(pb2, (C)); B3##S = LB(pb3, (C));

    for (int s = 0; s < 32; s += 4) {
      CONSUME(x)  if (s + 4 < 32) { RELOAD(x, s + 4) }
      CONSUME(y)  if (s + 5 < 32) { RELOAD(y, s + 5) }
      CONSUME(z)  if (s + 6 < 32) { RELOAD(z, s + 6) }
      CONSUME(w)  if (s + 7 < 32) { RELOAD(w, s + 7) }
    }
#undef CONSUME
#undef RELOAD
#undef LA
#undef LB

    const int prow0 = (lane >> 5) * 4;
    float* pw = P + q * 2176 + (ct * 32 + (lane & 31));
#pragma unroll
    for (int rr = 0; rr < 16; ++rr) {
      const int row = prow0 + (rr & 3) + 8 * (rr >> 2);
      pw[row * 68] = accA[rr] + accB[rr];
    }
  }
  __syncthreads();

  // ---- 512-thread epilogue: thread -> (row, 4 cols) ----
  {
    const int row = tid >> 4;
    const int j0l = (tid & 15) * 4;
    const int b   = TR * 32 + row;
    const int gc  = TC * 64 + j0l;

    float e0 = 0.f, e1 = 0.f, e2 = 0.f, e3 = 0.f;
    if (t > 0) {
#pragma unroll
      for (int qq = 0; qq < 4; ++qq) { // fixed order
        const float* pr = P + qq * 2176 + row * 68 + j0l;
        e0 += pr[0]; e1 += pr[1]; e2 += pr[2]; e3 += pr[3];
      }
    }

    const float* xb = x + ((size_t)b * Tq + t) * INq;
#pragma unroll
    for (int i = 0; i < INq; ++i) {
      float xv = xb[i];
      float4 wv4 = *(const float4*)(WiT + (size_t)i * Hq + gc);
      e0 = fmaf(xv, wv4.x, e0); e1 = fmaf(xv, wv4.y, e1);
      e2 = fmaf(xv, wv4.z, e2); e3 = fmaf(xv, wv4.w, e3);
    }

    float4 nz = *(const float4*)(noise + ((size_t)t * Bq + b) * Hq + gc);
    e0 += nz.x; e1 += nz.y; e2 += nz.z; e3 += nz.w;

    float4 hp = make_float4(0.f, 0.f, 0.f, 0.f);
    if (t > 0) hp = *(const float4*)(hprevF + (size_t)b * Hq + gc);

    float4 o;
    o.x = fmaf(fmaxf(e0, 0.f), 0.1f, 0.9f * hp.x);
    o.y = fmaf(fmaxf(e1, 0.f), 0.1f, 0.9f * hp.y);
    o.z = fmaf(fmaxf(e2, 0.f), 0.1f, 0.9f * hp.z);
    o.w = fmaf(fmaxf(e3, 0.f), 0.1f, 0.9f * hp.w);

    *(float4*)(out_h + ((size_t)b * Tq + t) * Hq + gc) = o;
    *(float4*)(houtF + (size_t)b * Hq + gc) = o;

    us4 p1v, p2v, p3v;
    float ov[4] = { o.x, o.y, o.z, o.w };
#pragma unroll
    for (int c = 0; c < 4; ++c) {
      unsigned short b1 = f32_to_bf16(ov[c]);
      float r1 = ov[c] - bf16_to_f32(b1);
      unsigned short b2 = f32_to_bf16(r1);
      float r2 = r1 - bf16_to_f32(b2);
      p1v[c] = b1; p2v[c] = b2; p3v[c] = f32_to_bf16(r2);
    }
    const size_t apo = ((size_t)((gc >> 4) * 8 + TR) * 64
                        + ((gc >> 3) & 1) * 32 + row) * 8 + (gc & 7);
    *(us4*)&o1[apo] = p1v;
    *(us4*)&o2[apo] = p2v;
    *(us4*)&o3[apo] = p3v;
  }
}

// ===========================================================================
// Fallback (R9 f32 path) if workspace too small.
// ===========================================================================
#define BKq 32
#define NST 16
__device__ __forceinline__ int swz(int row, int k) {
  return k ^ (((row >> 2) & 7) << 2);
}

template<bool SLAB>
__global__ __launch_bounds__(512, 2) void rnn_step(
    const float* __restrict__ x, const float* __restrict__ noise,
    const float* __restrict__ Wi2h, const float* __restrict__ Wrec,
    const float* __restrict__ Wh2o, float* __restrict__ out_h,
    float* __restrict__ out_o, const float* __restrict__ slabP,
    float* __restrict__ slabT, int t)
{
  constexpr size_t HSTR = SLAB ? (size_t)Hq : (size_t)Tq * Hq;
  __shared__ float smem[24576];
  const int wg  = blockIdx.x;
  const int tid = threadIdx.x;
  const int L  = (wg & 7) * 32 + (wg >> 3);
  const int TC = L >> 3;
  const int TR = L & 7;
  const int q  = tid >> 7;
  const int qt = tid & 127;
  const int tx = qt & 15;
  const int ty = qt >> 4;
  const int m0 = ty * 4, n0 = tx * 4;
  const int b0 = TR * 32 + m0;
  const int j0 = TC * 64 + n0;
  const int kb = q * 512;
  const float* hPrev = SLAB ? slabP : (out_h + (size_t)(t > 0 ? t - 1 : 0) * Hq);
  const int sm  = ((qt & 7) << 2) | ((qt >> 3) & 3);
  const int skh = ((qt >> 5) & 3) * 8;
  const int sn  = (((qt >> 5) & 1) << 5) | ((qt & 7) << 2) | ((qt >> 3) & 3);
  const int snk = ((qt >> 6) & 1) * 16;
  const float* gA = hPrev + (size_t)(TR * 32 + sm) * HSTR + kb + skh;
  const float* gB = Wrec + (size_t)(TC * 64 + sn) * Hq + kb + snk;
  float4 sA0, sA1, sB0, sB1, sB2, sB3;
  if (t > 0) {
    sA0 = *(const float4*)(gA);      sA1 = *(const float4*)(gA + 4);
    sB0 = *(const float4*)(gB);      sB1 = *(const float4*)(gB + 4);
    sB2 = *(const float4*)(gB + 8);  sB3 = *(const float4*)(gB + 12);
  }
  if (t > 0) {
    const int i4 = tid * 4;
    float4 hv = *(const float4*)(hPrev + (size_t)wg * HSTR + i4);
    float4 w0 = *(const float4*)(Wh2o + 0 * Hq + i4);
    float4 w1 = *(const float4*)(Wh2o + 1 * Hq + i4);
    float4 w2 = *(const float4*)(Wh2o + 2 * Hq + i4);
    float4 w3 = *(const float4*)(Wh2o + 3 * Hq + i4);
    float a0 = 0.f, a1 = 0.f, a2 = 0.f, a3 = 0.f;
    DOT4(a0, hv, w0); DOT4(a1, hv, w1); DOT4(a2, hv, w2); DOT4(a3, hv, w3);
#pragma unroll
    for (int m = 1; m <= 32; m <<= 1) {
      a0 += __shfl_xor(a0, m); a1 += __shfl_xor(a1, m);
      a2 += __shfl_xor(a2, m); a3 += __shfl_xor(a3, m);
    }
    if ((tid & 63) == 0) {
      const int w = tid >> 6;
      smem[w * 4 + 0] = a0; smem[w * 4 + 1] = a1;
      smem[w * 4 + 2] = a2; smem[w * 4 + 3] = a3;
    }
    __syncthreads();
    if (tid == 0) {
      float s0 = 0.f, s1 = 0.f, s2 = 0.f, s3 = 0.f;
#pragma unroll
      for (int w = 0; w < 8; ++w) {
        s0 += smem[w * 4 + 0]; s1 += smem[w * 4 + 1];
        s2 += smem[w * 4 + 2]; s3 += smem[w * 4 + 3];
      }
      float m  = fmaxf(fmaxf(s0, s1), fmaxf(s2, s3));
      float e0 = expf(s0 - m), e1 = expf(s1 - m);
      float e2 = expf(s2 - m), e3 = expf(s3 - m);
      float inv = 1.0f / (e0 + e1 + e2 + e3);
      float* op = out_o + ((size_t)wg * Tq + (t - 1)) * OUTq;
      op[0] = e0 * inv; op[1] = e1 * inv; op[2] = e2 * inv; op[3] = e3 * inv;
    }
    __syncthreads();
  }
  float acc00 = 0.f, acc01 = 0.f, acc02 = 0.f, acc03 = 0.f;
  float acc10 = 0.f, acc11 = 0.f, acc12 = 0.f, acc13 = 0.f;
  float acc20 = 0.f, acc21 = 0.f, acc22 = 0.f, acc23 = 0.f;
  float acc30 = 0.f, acc31 = 0.f, acc32 = 0.f, acc33 = 0.f;
  if (t > 0) {
    {
      float* aL = smem + q * 2048;
      float* bL = smem + 8192 + q * 4096;
      *(float4*)(aL + sm * 32 + swz(sm, skh))      = sA0;
      *(float4*)(aL + sm * 32 + swz(sm, skh + 4))  = sA1;
      *(float4*)(bL + sn * 32 + swz(sn, snk))      = sB0;
      *(float4*)(bL + sn * 32 + swz(sn, snk + 4))  = sB1;
      *(float4*)(bL + sn * 32 + swz(sn, snk + 8))  = sB2;
      *(float4*)(bL + sn * 32 + swz(sn, snk + 12)) = sB3;
    }
    __syncthreads();
    const int aKey = ty << 2;
    const int bKey = (tx & 7) << 2;
    for (int s = 0; s < NST; ++s) {
      const int buf = s & 1;
      if (s + 1 < NST) {
        const int o = (s + 1) * BKq;
        sA0 = *(const float4*)(gA + o);      sA1 = *(const float4*)(gA + o + 4);
        sB0 = *(const float4*)(gB + o);      sB1 = *(const float4*)(gB + o + 4);
        sB2 = *(const float4*)(gB + o + 8);  sB3 = *(const float4*)(gB + o + 12);
      }
      const float* aT = smem + q * 2048 + buf * 1024 + ty * 128;
      const float* bT = smem + 8192 + q * 4096 + buf * 2048 + tx * 128;
#pragma unroll
      for (int k4 = 0; k4 < BKq; k4 += 4) {
        const float* ap = aT + (k4 ^ aKey);
        const float* bp = bT + (k4 ^ bKey);
        float4 A0 = *(const float4*)(ap);
        float4 A1 = *(const float4*)(ap + 32);
        float4 A2 = *(const float4*)(ap + 64);
        float4 A3 = *(const float4*)(ap + 96);
        float4 Bv0 = *(const float4*)(bp);
        float4 Bv1 = *(const float4*)(bp + 32);
        float4 Bv2 = *(const float4*)(bp + 64);
        float4 Bv3 = *(const float4*)(bp + 96);
        DOT4(acc00, A0, Bv0); DOT4(acc01, A0, Bv1); DOT4(acc02, A0, Bv2); DOT4(acc03, A0, Bv3);
        DOT4(acc10, A1, Bv0); DOT4(acc11, A1, Bv1); DOT4(acc12, A1, Bv2); DOT4(acc13, A1, Bv3);
        DOT4(acc20, A2, Bv0); DOT4(acc21, A2, Bv1); DOT4(acc22, A2, Bv2); DOT4(acc23, A2, Bv3);
        DOT4(acc30, A3, Bv0); DOT4(acc31, A3, Bv1); DOT4(acc32, A3, Bv2); DOT4(acc33, A3, Bv3);
      }
      if (s + 1 < NST) {
        float* aL = smem + q * 2048 + (buf ^ 1) * 1024;
        float* bL = smem + 8192 + q * 4096 + (buf ^ 1) * 2048;
        *(float4*)(aL + sm * 32 + swz(sm, skh))      = sA0;
        *(float4*)(aL + sm * 32 + swz(sm, skh + 4))  = sA1;
        *(float4*)(bL + sn * 32 + swz(sn, snk))      = sB0;
        *(float4*)(bL + sn * 32 + swz(sn, snk + 4))  = sB1;
        *(float4*)(bL + sn * 32 + swz(sn, snk + 8))  = sB2;
        *(float4*)(bL + sn * 32 + swz(sn, snk + 12)) = sB3;
      }
      __syncthreads();
    }
  }
  {
    const int ilo = q * 8;
    const int ihi = (q == 3) ? INq : (ilo + 8);
    const float* xb = x + (size_t)b0 * Tq * INq + (size_t)t * INq;
    const float* wv = Wi2h + (size_t)j0 * INq;
    const size_t xs = (size_t)Tq * INq;
    for (int i = ilo; i < ihi; ++i) {
      float x0 = xb[i], x1 = xb[xs + i], x2 = xb[2 * xs + i], x3 = xb[3 * xs + i];
      float w0 = wv[i], w1 = wv[INq + i], w2 = wv[2 * INq + i], w3 = wv[3 * INq + i];
      acc00 = fmaf(x0, w0, acc00); acc01 = fmaf(x0, w1, acc01);
      acc02 = fmaf(x0, w2, acc02); acc03 = fmaf(x0, w3, acc03);
      acc10 = fmaf(x1, w0, acc10); acc11 = fmaf(x1, w1, acc11);
      acc12 = fmaf(x1, w2, acc12); acc13 = fmaf(x1, w3, acc13);
      acc20 = fmaf(x2, w0, acc20); acc21 = fmaf(x2, w1, acc21);
      acc22 = fmaf(x2, w2, acc22); acc23 = fmaf(x2, w3, acc23);
      acc30 = fmaf(x3, w0, acc30); acc31 = fmaf(x3, w1, acc31);
      acc32 = fmaf(x3, w2, acc32); acc33 = fmaf(x3, w3, acc33);
    }
  }
  if (q != 0) {
    float* rd = smem + (q - 1) * 2560 + qt * 20;
    *(float4*)(rd + 0)  = make_float4(acc00, acc01, acc02, acc03);
    *(float4*)(rd + 4)  = make_float4(acc10, acc11, acc12, acc13);
    *(float4*)(rd + 8)  = make_float4(acc20, acc21, acc22, acc23);
    *(float4*)(rd + 12) = make_float4(acc30, acc31, acc32, acc33);
  }
  __syncthreads();
  if (q == 0) {
#pragma unroll
    for (int p = 0; p < 3; ++p) {
      const float* rd = smem + p * 2560 + qt * 20;
      float4 r0 = *(const float4*)(rd + 0),  r1 = *(const float4*)(rd + 4);
      float4 r2 = *(const float4*)(rd + 8),  r3 = *(const float4*)(rd + 12);
      acc00 += r0.x; acc01 += r0.y; acc02 += r0.z; acc03 += r0.w;
      acc10 += r1.x; acc11 += r1.y; acc12 += r1.z; acc13 += r1.w;
      acc20 += r2.x; acc21 += r2.y; acc22 += r2.z; acc23 += r2.w;
      acc30 += r3.x; acc31 += r3.y; acc32 += r3.z; acc33 += r3.w;
    }
    const float* nzb = noise + ((size_t)t * Bq + b0) * Hq + j0;
    float4 nz0 = *(const float4*)(nzb);
    float4 nz1 = *(const float4*)(nzb + Hq);
    float4 nz2 = *(const float4*)(nzb + 2 * Hq);
    float4 nz3 = *(const float4*)(nzb + 3 * Hq);
    float4 hp0 = make_float4(0.f,0.f,0.f,0.f), hp1 = hp0, hp2 = hp0, hp3 = hp0;
    if (t > 0) {
      hp0 = *(const float4*)(hPrev + (size_t)(b0 + 0) * HSTR + j0);
      hp1 = *(const float4*)(hPrev + (size_t)(b0 + 1) * HSTR + j0);
      hp2 = *(const float4*)(hPrev + (size_t)(b0 + 2) * HSTR + j0);
      hp3 = *(const float4*)(hPrev + (size_t)(b0 + 3) * HSTR + j0);
    }
    float4 o0, o1, o2, o3;
    o0.x = fmaf(fmaxf(acc00 + nz0.x, 0.f), 0.1f, 0.9f * hp0.x);
    o0.y = fmaf(fmaxf(acc01 + nz0.y, 0.f), 0.1f, 0.9f * hp0.y);
    o0.z = fmaf(fmaxf(acc02 + nz0.z, 0.f), 0.1f, 0.9f * hp0.z);
    o0.w = fmaf(fmaxf(acc03 + nz0.w, 0.f), 0.1f, 0.9f * hp0.w);
    o1.x = fmaf(fmaxf(acc10 + nz1.x, 0.f), 0.1f, 0.9f * hp1.x);
    o1.y = fmaf(fmaxf(acc11 + nz1.y, 0.f), 0.1f, 0.9f * hp1.y);
    o1.z = fmaf(fmaxf(acc12 + nz1.z, 0.f), 0.1f, 0.9f * hp1.z);
    o1.w = fmaf(fmaxf(acc13 + nz1.w, 0.f), 0.1f, 0.9f * hp1.w);
    o2.x = fmaf(fmaxf(acc20 + nz2.x, 0.f), 0.1f, 0.9f * hp2.x);
    o2.y = fmaf(fmaxf(acc21 + nz2.y, 0.f), 0.1f, 0.9f * hp2.y);
    o2.z = fmaf(fmaxf(acc22 + nz2.z, 0.f), 0.1f, 0.9f * hp2.z);
    o2.w = fmaf(fmaxf(acc23 + nz2.w, 0.f), 0.1f, 0.9f * hp2.w);
    o3.x = fmaf(fmaxf(acc30 + nz3.x, 0.f), 0.1f, 0.9f * hp3.x);
    o3.y = fmaf(fmaxf(acc31 + nz3.y, 0.f), 0.1f, 0.9f * hp3.y);
    o3.z = fmaf(fmaxf(acc32 + nz3.z, 0.f), 0.1f, 0.9f * hp3.z);
    o3.w = fmaf(fmaxf(acc33 + nz3.w, 0.f), 0.1f, 0.9f * hp3.w);
    float* oh = out_h + (size_t)b0 * Tq * Hq + (size_t)t * Hq + j0;
    *(float4*)(oh)                       = o0;
    *(float4*)(oh + (size_t)Tq * Hq)     = o1;
    *(float4*)(oh + (size_t)2 * Tq * Hq) = o2;
    *(float4*)(oh + (size_t)3 * Tq * Hq) = o3;
    if (SLAB) {
      float* sl = slabT + (size_t)b0 * Hq + j0;
      *(float4*)(sl)            = o0;
      *(float4*)(sl + Hq)       = o1;
      *(float4*)(sl + 2 * Hq)   = o2;
      *(float4*)(sl + 3 * Hq)   = o3;
    }
  }
}

extern "C" void kernel_launch(void* const* d_in, const int* in_sizes, int n_in,
                              void* d_out, int out_size, void* d_ws, size_t ws_size,
                              hipStream_t stream) {
  const float* x     = (const float*)d_in[0];
  const float* noise = (const float*)d_in[1];
  const float* Wi2h  = (const float*)d_in[2];
  const float* Wrec  = (const float*)d_in[3];
  const float* Wh2o  = (const float*)d_in[4];
  float* out_h = (float*)d_out;
  float* out_o = out_h + (size_t)Bq * Tq * Hq;

  if (ws_size >= WS_TOTAL) {
    char* ws = (char*)d_ws;
    unsigned short* w1 = (unsigned short*)(ws + WS_W1);
    unsigned short* w2 = (unsigned short*)(ws + WS_W2);
    unsigned short* w3 = (unsigned short*)(ws + WS_W3);
    float* slabF[2] = { (float*)(ws + WS_SLABF0), (float*)(ws + WS_SLABF1) };
    float* WiT = (float*)(ws + WS_WIT);
    unsigned short* ap[2][3];
    for (int pp = 0; pp < 2; ++pp)
      for (int p = 0; p < 3; ++p)
        ap[pp][p] = (unsigned short*)(ws + WS_APARTS + ((size_t)(pp * 3 + p)) * 1048576ull);

    conv_wrec<<<1024, 256, 0, stream>>>(Wrec, w1, w2, w3);
    conv_wi<<<(INq * Hq + 255) / 256, 256, 0, stream>>>(Wi2h, WiT);

    for (int t = 0; t < Tq; ++t) {
      const int pc = t & 1, pp = pc ^ 1;
      rnn_step_mfma<<<256, 512, 0, stream>>>(
          x, noise, WiT, Wh2o, w1, w2, w3,
          slabF[pp], ap[pp][0], ap[pp][1], ap[pp][2],
          slabF[pc], ap[pc][0], ap[pc][1], ap[pc][2],
          out_h, out_o, t);
    }
    proj_tail<<<4, 256, 0, stream>>>(slabF[(Tq - 1) & 1], (size_t)Hq,
                                     Wh2o, out_o, Tq - 1);
  } else {
    const bool use_ws = ws_size >= (size_t)2 * Bq * Hq * sizeof(float);
    float* slab0 = (float*)d_ws;
    float* slab1 = slab0 + (size_t)Bq * Hq;
    if (use_ws) {
      for (int t = 0; t < Tq; ++t) {
        const float* sp = (t > 0) ? (((t - 1) & 1) ? slab1 : slab0) : nullptr;
        float*       st = (t & 1) ? slab1 : slab0;
        rnn_step<true><<<256, 512, 0, stream>>>(x, noise, Wi2h, Wrec, Wh2o,
                                                out_h, out_o, sp, st, t);
      }
      const float* hb = ((Tq - 1) & 1) ? slab1 : slab0;
      proj_tail<<<4, 256, 0, stream>>>(hb, (size_t)Hq, Wh2o, out_o, Tq - 1);
    } else {
      for (int t = 0; t < Tq; ++t) {
        rnn_step<false><<<256, 512, 0, stream>>>(x, noise, Wi2h, Wrec, Wh2o,
                                                 out_h, out_o, nullptr, nullptr, t);
      }
      proj_tail<<<4, 256, 0, stream>>>(out_h + (size_t)(Tq - 1) * Hq,
                                       (size_t)Tq * Hq, Wh2o, out_o, Tq - 1);
    }
  }
}